// Round 18
// baseline (380.243 us; speedup 1.0000x reference)
//
#include <hip/hip_runtime.h>

#define DM    1024
#define DFF   4096
#define SEQ   2048
#define BATCH 4
#define NROWS (BATCH * SEQ)   // 8192
#define HEADS 16
#define DKH   64
#define KSTR  (2 * DM)        // fused QK row stride

typedef __attribute__((ext_vector_type(4))) float          f32x4;
typedef __attribute__((ext_vector_type(8))) __bf16         bf16x8;
typedef __attribute__((ext_vector_type(8))) unsigned short u16x8;
typedef __attribute__((ext_vector_type(4))) unsigned short u16x4;

static __device__ __forceinline__ unsigned short f2bf(float f) {
  unsigned u = __builtin_bit_cast(unsigned, f);
  u += 0x7fffu + ((u >> 16) & 1u);   // round-to-nearest-even
  return (unsigned short)(u >> 16);
}

// ---------------- fp32 -> bf16 weight conversion (all 6 tensors, 1 launch) ----------------
struct CvtJobs {
  const float* src[6];
  unsigned short* dst[6];
};
// segment sizes in float4 units: wq,wk,wv,wo = 262144 f4 each, w1,w2 = 1048576 f4.
__constant__ const unsigned c_cum[6] = {262144u, 524288u, 786432u, 1048576u, 2097152u, 3145728u};

__global__ __launch_bounds__(256) void k_f2bf_all(CvtJobs jobs) {
  unsigned i = blockIdx.x * blockDim.x + threadIdx.x;
  if (i >= 3145728u) return;
  int j = 0;
#pragma unroll
  for (int s = 0; s < 6; ++s) j += (i >= c_cum[s]) ? 1 : 0;
  const unsigned base = (j == 0) ? 0u : c_cum[j - 1];
  const unsigned loc  = i - base;
  float4 v = reinterpret_cast<const float4*>(jobs.src[j])[loc];
  ushort4 o;
  o.x = f2bf(v.x); o.y = f2bf(v.y); o.z = f2bf(v.z); o.w = f2bf(v.w);
  reinterpret_cast<ushort4*>(jobs.dst[j])[loc] = o;
}

// ---------------- RMSNorm: fp32 in -> bf16 out ----------------
__global__ __launch_bounds__(256) void k_rmsnorm(const float* __restrict__ x,
                                                 const float* __restrict__ w,
                                                 unsigned short* __restrict__ out) {
  const int row = blockIdx.x;
  const float4 v = reinterpret_cast<const float4*>(x + (size_t)row * DM)[threadIdx.x];
  float ss = v.x * v.x + v.y * v.y + v.z * v.z + v.w * v.w;
#pragma unroll
  for (int off = 32; off > 0; off >>= 1) ss += __shfl_down(ss, off);
  __shared__ float red[4];
  if ((threadIdx.x & 63) == 0) red[threadIdx.x >> 6] = ss;
  __syncthreads();
  const float tot  = red[0] + red[1] + red[2] + red[3];
  const float rden = rsqrtf(tot * (1.0f / DM) + 1e-5f);
  const float4 wv = reinterpret_cast<const float4*>(w)[threadIdx.x];
  ushort4 o;
  o.x = f2bf(v.x * wv.x * rden);
  o.y = f2bf(v.y * wv.y * rden);
  o.z = f2bf(v.z * wv.z * rden);
  o.w = f2bf(v.w * wv.w * rden);
  reinterpret_cast<ushort4*>(out + (size_t)row * DM)[threadIdx.x] = o;
}

// ---------------- NT GEMM: C(MxN) = A(MxK,bf16) * B(NxK,bf16)^T ----------------
// Round-9-proven structure, templated on tile width TN (128/256) and K-step
// BK (32/64). 128xTN tile, 4 waves (2x2); double-buffered 2-phase K-loop;
// row-major LDS with COALESCED staging + granule XOR.
// r10 lesson: never trade staging coalescing for LDS-conflict-freedom.
// r13: TN=256 (only when grid >= 2 blocks/CU). r16: BK=64 for TN=128
// instances (barrier-stall bound; halves barriers/FLOP; per-kk fragment
// loads keep VGPR under the 2-wave cap -- r14 spill lesson).
// EPI: 0 bf16, 1 fp32+res, 2 gelu, 3 Q-prescale.
template <int EPI, int TN, int BK>
__global__ __launch_bounds__(256, 2) void k_gemm_nt(const unsigned short* __restrict__ A,
                                                    const unsigned short* __restrict__ B,
                                                    void* __restrict__ Cv,
                                                    const float* __restrict__ res,
                                                    int M, int N, int K) {
  constexpr int NW = TN / 128;            // B-tile row multiple
  alignas(16) __shared__ unsigned short As[2][128 * BK];
  alignas(16) __shared__ unsigned short Bs[2][128 * NW * BK];
  const int t  = threadIdx.x;
  const int w  = t >> 6;
  const int l  = t & 63;
  const int wr = w >> 1, wc = w & 1;
  const int lr = l & 15, lk = l >> 4;

  const unsigned bid = blockIdx.y * gridDim.x + blockIdx.x;
  const unsigned cpx = (gridDim.x * gridDim.y) >> 3;
  const unsigned sw  = (bid & 7) * cpx + (bid >> 3);
  const int m0 = (int)(sw / gridDim.x) * 128;
  const int n0 = (int)(sw % gridDim.x) * TN;

  auto stage = [&](int buf, int k0) {
    if constexpr (BK == 32) {
      const int srow = t >> 2;                  // 0..63, 4 lanes per 64B row
      const int sgr  = (t & 3) ^ (srow & 3);    // pre-swizzled source granule
#pragma unroll
      for (int r = 0; r < 2; ++r) {
        const unsigned short* ga = A + (size_t)(m0 + r * 64 + srow) * K + k0 + 8 * sgr;
        __builtin_amdgcn_global_load_lds((__attribute__((address_space(1))) void*)ga,
                                         (__attribute__((address_space(3))) void*)(&As[buf][r * 2048 + w * 512]),
                                         16, 0, 0);
      }
#pragma unroll
      for (int r = 0; r < 2 * NW; ++r) {
        const unsigned short* gb = B + (size_t)(n0 + r * 64 + srow) * K + k0 + 8 * sgr;
        __builtin_amdgcn_global_load_lds((__attribute__((address_space(1))) void*)gb,
                                         (__attribute__((address_space(3))) void*)(&Bs[buf][r * 2048 + w * 512]),
                                         16, 0, 0);
      }
    } else {
      // BK == 64 (TN==128): 128B rows, 8 lanes per row; 4 issues cover 128 rows
      const int srow8 = l >> 3;                 // row within wave's 8-row group
      const int g     = l & 7;
#pragma unroll
      for (int i = 0; i < 4; ++i) {
        const int row = i * 32 + w * 8 + srow8;
        const int sg  = g ^ (row & 7);          // pre-swizzled source granule
        const unsigned short* ga = A + (size_t)(m0 + row) * K + k0 + 8 * sg;
        __builtin_amdgcn_global_load_lds((__attribute__((address_space(1))) void*)ga,
                                         (__attribute__((address_space(3))) void*)(&As[buf][i * 2048 + w * 512]),
                                         16, 0, 0);
        const unsigned short* gb = B + (size_t)(n0 + row) * K + k0 + 8 * sg;
        __builtin_amdgcn_global_load_lds((__attribute__((address_space(1))) void*)gb,
                                         (__attribute__((address_space(3))) void*)(&Bs[buf][i * 2048 + w * 512]),
                                         16, 0, 0);
      }
    }
  };

  f32x4 acc[4][4 * NW] = {};

  stage(0, 0);
  const int nIt = K / BK;
  for (int it = 0; it < nIt; ++it) {
    const int buf = it & 1;
    __syncthreads();                          // drains vmcnt -> buf ready; WAR-safe
    if (it + 1 < nIt) stage(buf ^ 1, (it + 1) * BK);

    if constexpr (BK == 32) {
      bf16x8 af[4], bf[4 * NW];
#pragma unroll
      for (int m = 0; m < 4; ++m)
        af[m] = *reinterpret_cast<const bf16x8*>(
            &As[buf][(wr * 64 + m * 16 + lr) * 32 + 8 * (lk ^ (lr & 3))]);
#pragma unroll
      for (int n = 0; n < 4 * NW; ++n)
        bf[n] = *reinterpret_cast<const bf16x8*>(
            &Bs[buf][(wc * 64 * NW + n * 16 + lr) * 32 + 8 * (lk ^ (lr & 3))]);
#pragma unroll
      for (int m = 0; m < 4; ++m)
#pragma unroll
        for (int n = 0; n < 4 * NW; ++n)
          acc[m][n] = __builtin_amdgcn_mfma_f32_16x16x32_bf16(af[m], bf[n], acc[m][n], 0, 0, 0);
    } else {
      // BK == 64: two K=32 slices; load fragments per-slice to bound VGPR
#pragma unroll
      for (int kk = 0; kk < 2; ++kk) {
        bf16x8 af[4], bf[4];
#pragma unroll
        for (int m = 0; m < 4; ++m)
          af[m] = *reinterpret_cast<const bf16x8*>(
              &As[buf][(wr * 64 + m * 16 + lr) * 64 + 8 * ((4 * kk + lk) ^ (lr & 7))]);
#pragma unroll
        for (int n = 0; n < 4; ++n)
          bf[n] = *reinterpret_cast<const bf16x8*>(
              &Bs[buf][(wc * 64 + n * 16 + lr) * 64 + 8 * ((4 * kk + lk) ^ (lr & 7))]);
#pragma unroll
        for (int m = 0; m < 4; ++m)
#pragma unroll
          for (int n = 0; n < 4; ++n)
            acc[m][n] = __builtin_amdgcn_mfma_f32_16x16x32_bf16(af[m], bf[n], acc[m][n], 0, 0, 0);
      }
    }
  }

#pragma unroll
  for (int m = 0; m < 4; ++m) {
#pragma unroll
    for (int n = 0; n < 4 * NW; ++n) {
#pragma unroll
      for (int r = 0; r < 4; ++r) {
        const size_t row = (size_t)(m0 + wr * 64 + m * 16 + lk * 4 + r);
        const size_t col = (size_t)(n0 + wc * 64 * NW + n * 16 + lr);
        const float a = acc[m][n][r];
        if constexpr (EPI == 0) {
          ((unsigned short*)Cv)[row * N + col] = f2bf(a);
        } else if constexpr (EPI == 1) {
          ((float*)Cv)[row * N + col] = a + res[row * N + col];
        } else if constexpr (EPI == 2) {
          // GELU, tanh/exp2 form: g = h - h/(exp2(h*(a1+b1*h^2))+1)
          const float h2 = a * a;
          const float e  = exp2f(a * (2.30221535f + 0.10295355f * h2));
          const float g  = a - a / (e + 1.0f);
          ((unsigned short*)Cv)[row * N + col] = f2bf(g);
        } else {
          const float sc = (col < DM) ? 0.18033688011f : 1.0f;  // 0.125*log2(e) on Q
          ((unsigned short*)Cv)[row * N + col] = f2bf(a * sc);
        }
      }
    }
  }
}

// ---------------- Flash causal attention (64-row folded q-pairs) ----------------
// r13/r17 structure, ROUND-18 CHANGE: K/V double-buffer removed. Evidence:
// r5 (single-buffer, 2 barriers/tile, 168us) vs r6 (dbuf, 1 barrier/tile,
// 172us) -- dbuf was NEUTRAL; staging latency is hidden by co-resident
// blocks. Halving Ks/Vt cuts LDS 48->32 KB -> 4 blocks/CU (grid-limited),
// +33% TLP for this latency-bound kernel. bounds stays (256,3) so regalloc
// is untouched (72 VGPR << 128 needed for 4 waves/SIMD) -- avoids the r14
// forced-spill mode; residency is LDS/grid-driven.
// Tree-reduced softmax (max3 fusion + pairwise sums), setprio around MFMA,
// Q pre-scaled by 0.125*log2e, defer-max, XCD-grouped blocks (bid%8 = h%8).
__global__ __launch_bounds__(256, 3) void k_attn(const unsigned short* __restrict__ QK,
                                                 const unsigned short* __restrict__ VT,
                                                 unsigned short* __restrict__ O) {
  const int h   = blockIdx.x;
  const int qtA = blockIdx.y;                 // 0..15
  const int qtB = 31 - qtA;                   // 31..16
  const int b   = blockIdx.z;
  const int t  = threadIdx.x, w = t >> 6, l = t & 63;
  const int lr = l & 15, lk = l >> 4;
  const size_t rowB = (size_t)b * SEQ;
  const int hoff  = h * DKH;
  const int qw2[2] = { qtA * 64 + 16 * w, qtB * 64 + 16 * w };

  alignas(16) __shared__ unsigned short Ks[64 * 64];       // 8 KB
  alignas(16) __shared__ unsigned short Vt[64 * 64];       // 8 KB
  alignas(16) __shared__ unsigned short Ps[2][4][16 * 64]; // 16 KB

  char* const KsB = (char*)Ks;
  char* const VtB = (char*)Vt;

  auto stage = [&](int kb2) {
#pragma unroll
    for (int half = 0; half < 2; ++half) {
      const int srow = w * 16 + half * 8 + (l >> 3);
      const int sgr  = (l & 7) ^ (srow & 7);   // pre-swizzled source granule
      const unsigned short* gk = QK + (size_t)(rowB + kb2 + srow) * KSTR + DM + hoff + 8 * sgr;
      __builtin_amdgcn_global_load_lds((__attribute__((address_space(1))) void*)gk,
                                       (__attribute__((address_space(3))) void*)(KsB + w * 2048 + half * 1024),
                                       16, 0, 0);
      const unsigned short* gv = VT + (size_t)(hoff + srow) * NROWS + rowB + kb2 + 8 * sgr;
      __builtin_amdgcn_global_load_lds((__attribute__((address_space(1))) void*)gv,
                                       (__attribute__((address_space(3))) void*)(VtB + w * 2048 + half * 1024),
                                       16, 0, 0);
    }
  };

  bf16x8 qf[2][2];
#pragma unroll
  for (int s = 0; s < 2; ++s)
#pragma unroll
    for (int kk = 0; kk < 2; ++kk)
      qf[s][kk] = *reinterpret_cast<const bf16x8*>(
          QK + (rowB + qw2[s] + lr) * KSTR + hoff + 32 * kk + 8 * lk);

  f32x4 oacc[2][4] = {};
  float mrun[2] = {-1e30f, -1e30f};
  float lrun[2] = {0.0f, 0.0f};

  const int ktmax = qtB;
  for (int kt = 0; kt <= ktmax; ++kt) {
    const int kbase = kt * 64;
    __syncthreads();                 // WAR: previous tile's LDS reads complete
    stage(kbase);
    __syncthreads();                 // vmcnt drained -> tile visible

    const bool act[2] = { kbase <= qw2[0] + 15, kbase <= qw2[1] + 15 };

    f32x4 sacc[2][4] = {};
    __builtin_amdgcn_s_setprio(1);
#pragma unroll
    for (int tt = 0; tt < 4; ++tt) {
      bf16x8 kf0 = *reinterpret_cast<const bf16x8*>(KsB + (16 * tt + lr) * 128 + 16 * ((lk + 0) ^ (lr & 7)));
      bf16x8 kf1 = *reinterpret_cast<const bf16x8*>(KsB + (16 * tt + lr) * 128 + 16 * ((lk + 4) ^ (lr & 7)));
#pragma unroll
      for (int s = 0; s < 2; ++s) {
        if (!act[s]) continue;
        sacc[s][tt] = __builtin_amdgcn_mfma_f32_16x16x32_bf16(kf0, qf[s][0], sacc[s][tt], 0, 0, 0);
        sacc[s][tt] = __builtin_amdgcn_mfma_f32_16x16x32_bf16(kf1, qf[s][1], sacc[s][tt], 0, 0, 0);
      }
    }
    __builtin_amdgcn_s_setprio(0);

#pragma unroll
    for (int s = 0; s < 2; ++s) {
      if (!act[s]) continue;
      const int qw = qw2[s];
      char* const PsSB = (char*)(Ps[s][w]);
      const int qg = qw + lr;
      float sv[4][4];
      if (kbase + 63 > qw) {
#pragma unroll
        for (int tt = 0; tt < 4; ++tt)
#pragma unroll
          for (int r = 0; r < 4; ++r) {
            const int kg = kbase + 16 * tt + 4 * lk + r;
            sv[tt][r] = (kg > qg) ? -1e30f : sacc[s][tt][r];
          }
      } else {
#pragma unroll
        for (int tt = 0; tt < 4; ++tt)
#pragma unroll
          for (int r = 0; r < 4; ++r) sv[tt][r] = sacc[s][tt][r];
      }
      // fmax tree (depth 3; nested triples fuse to v_max3_f32)
      const float a0 = fmaxf(fmaxf(sv[0][0], sv[0][1]), sv[0][2]);
      const float a1 = fmaxf(fmaxf(sv[0][3], sv[1][0]), sv[1][1]);
      const float a2 = fmaxf(fmaxf(sv[1][2], sv[1][3]), sv[2][0]);
      const float a3 = fmaxf(fmaxf(sv[2][1], sv[2][2]), sv[2][3]);
      const float a4 = fmaxf(fmaxf(sv[3][0], sv[3][1]), sv[3][2]);
      float tm = fmaxf(fmaxf(fmaxf(a0, a1), a2), fmaxf(fmaxf(a3, a4), sv[3][3]));
      tm = fmaxf(tm, __shfl_xor(tm, 16));
      tm = fmaxf(tm, __shfl_xor(tm, 32));
      float mref = mrun[s];
      if (__any(tm > mref + 8.0f)) {            // defer-max
        const float mnew  = fmaxf(mref, tm);
        const float alpha = exp2f(mref - mnew);
#pragma unroll
        for (int r = 0; r < 4; ++r) {
          const float ar = __shfl(alpha, 4 * lk + r);
#pragma unroll
          for (int dn = 0; dn < 4; ++dn) oacc[s][dn][r] *= ar;
        }
        lrun[s] *= alpha;
        mrun[s] = mnew;
        mref = mnew;
      }
      float p[4][4];
      unsigned short pb[4][4];
#pragma unroll
      for (int tt = 0; tt < 4; ++tt)
#pragma unroll
        for (int r = 0; r < 4; ++r) {
          p[tt][r] = exp2f(sv[tt][r] - mref);   // bounded by 2^8
          pb[tt][r] = __builtin_bit_cast(unsigned short, static_cast<__bf16>(p[tt][r]));
        }
      // pairwise sum tree (depth 4)
      float t0 = (p[0][0] + p[0][1]) + (p[0][2] + p[0][3]);
      float t1 = (p[1][0] + p[1][1]) + (p[1][2] + p[1][3]);
      float t2 = (p[2][0] + p[2][1]) + (p[2][2] + p[2][3]);
      float t3 = (p[3][0] + p[3][1]) + (p[3][2] + p[3][3]);
      float ts = (t0 + t1) + (t2 + t3);
      ts += __shfl_xor(ts, 16);
      ts += __shfl_xor(ts, 32);
      lrun[s] += ts;
#pragma unroll
      for (int tt = 0; tt < 4; ++tt) {
        u16x4 pw = {pb[tt][0], pb[tt][1], pb[tt][2], pb[tt][3]};
        *reinterpret_cast<u16x4*>(
            PsSB + lr * 128 + ((32 * tt + 8 * lk) ^ (16 * (lr & 7)))) = pw;
      }
    }

    // order P stores before the TBAA-distinct typed re-reads below
    asm volatile("" ::: "memory");

#pragma unroll
    for (int kk = 0; kk < 2; ++kk) {
      bf16x8 vf[4];
#pragma unroll
      for (int dn = 0; dn < 4; ++dn)
        vf[dn] = *reinterpret_cast<const bf16x8*>(
            VtB + (16 * dn + lr) * 128 + 16 * ((4 * kk + lk) ^ (lr & 7)));
      __builtin_amdgcn_s_setprio(1);
#pragma unroll
      for (int s = 0; s < 2; ++s) {
        if (!act[s]) continue;
        char* const PsSB = (char*)(Ps[s][w]);
        bf16x8 pa = *reinterpret_cast<const bf16x8*>(
            PsSB + lr * 128 + ((64 * kk + 16 * lk) ^ (16 * (lr & 7))));
#pragma unroll
        for (int dn = 0; dn < 4; ++dn)
          oacc[s][dn] = __builtin_amdgcn_mfma_f32_16x16x32_bf16(pa, vf[dn], oacc[s][dn], 0, 0, 0);
      }
      __builtin_amdgcn_s_setprio(0);
    }

    // order PV's P reads before next iteration's P stores (same-wave WAR on Ps)
    asm volatile("" ::: "memory");
  }

#pragma unroll
  for (int s = 0; s < 2; ++s)
#pragma unroll
    for (int r = 0; r < 4; ++r) {
      const float li = 1.0f / __shfl(lrun[s], 4 * lk + r);
      const size_t row = rowB + qw2[s] + 4 * lk + r;
#pragma unroll
      for (int dn = 0; dn < 4; ++dn)
        O[row * DM + hoff + 16 * dn + lr] = f2bf(oacc[s][dn][r] * li);
    }
}

// ---------------- launch ----------------
extern "C" void kernel_launch(void* const* d_in, const int* in_sizes, int n_in,
                              void* d_out, int out_size, void* d_ws, size_t ws_size,
                              hipStream_t stream) {
  const float* x   = (const float*)d_in[0];
  const float* ln1 = (const float*)d_in[1];
  const float* ln2 = (const float*)d_in[2];
  const float* wq  = (const float*)d_in[3];
  const float* wk  = (const float*)d_in[4];
  const float* wv  = (const float*)d_in[5];
  const float* wo  = (const float*)d_in[6];
  const float* w1  = (const float*)d_in[7];
  const float* w2  = (const float*)d_in[8];

  char* ws = (char*)d_ws;
  size_t off = 0;
  auto take = [&](size_t bytes) { void* p = ws + off; off += bytes; return p; };
  unsigned short* wqkb = (unsigned short*)take((size_t)2 * DM * DM * 2);   // 4 MB (Q,K fused)
  unsigned short* wvb  = (unsigned short*)take((size_t)DM * DM * 2);       // 2 MB
  unsigned short* wob  = (unsigned short*)take((size_t)DM * DM * 2);       // 2 MB
  unsigned short* w1b  = (unsigned short*)take((size_t)DFF * DM * 2);      // 8 MB
  unsigned short* w2b  = (unsigned short*)take((size_t)DM * DFF * 2);      // 8 MB
  unsigned short* qk   = (unsigned short*)take((size_t)NROWS * 2 * DM * 2); // 32 MB
  unsigned short* xn   = (unsigned short*)take((size_t)NROWS * DM * 2);    // 16 MB (ln1 out, reused attn-out)
  unsigned short* vtb  = (unsigned short*)take((size_t)DM * NROWS * 2);    // 16 MB V^T [DM][NROWS]
  float*          yb   = (float*)take((size_t)NROWS * DM * 4);             // 32 MB fp32 residual
  unsigned short* hb   = (unsigned short*)take((size_t)NROWS * DFF * 2);   // 64 MB
  unsigned short* yn   = qk;   // ln2 out aliases qk (dead after attn)

  // one fused weight-conversion dispatch (segment order matches c_cum)
  CvtJobs jobs;
  jobs.src[0] = wq;  jobs.dst[0] = wqkb;
  jobs.src[1] = wk;  jobs.dst[1] = wqkb + (size_t)DM * DM;
  jobs.src[2] = wv;  jobs.dst[2] = wvb;
  jobs.src[3] = wo;  jobs.dst[3] = wob;
  jobs.src[4] = w1;  jobs.dst[4] = w1b;
  jobs.src[5] = w2;  jobs.dst[5] = w2b;
  k_f2bf_all<<<dim3(3145728u / 256u), dim3(256), 0, stream>>>(jobs);

  k_rmsnorm<<<dim3(NROWS), dim3(256), 0, stream>>>(x, ln1, xn);

  // fused QK projection (EPI3: Q columns pre-scaled), 128x256 tile, BK=32
  k_gemm_nt<3, 256, 32><<<dim3(2 * DM / 256, NROWS / 128), dim3(256), 0, stream>>>(
      xn, wqkb, qk, nullptr, NROWS, 2 * DM, DM);

  // V^T directly: VT[DM][NROWS] = wv @ xn^T (operands swapped), 128x128, BK=64
  k_gemm_nt<0, 128, 64><<<dim3(NROWS / 128, DM / 128), dim3(256), 0, stream>>>(
      wvb, xn, vtb, nullptr, DM, NROWS, DM);

  k_attn<<<dim3(HEADS, 16, BATCH), dim3(256), 0, stream>>>(qk, vtb, xn);

  // WO projection + residual: 128x128, BK=64
  k_gemm_nt<1, 128, 64><<<dim3(DM / 128, NROWS / 128), dim3(256), 0, stream>>>(
      xn, wob, yb, x, NROWS, DM, DM);

  k_rmsnorm<<<dim3(NROWS), dim3(256), 0, stream>>>(yb, ln2, yn);

  // FFN1: 128x256 tile, BK=32 (grid 16x64 = 1024 blocks)
  k_gemm_nt<2, 256, 32><<<dim3(DFF / 256, NROWS / 128), dim3(256), 0, stream>>>(
      yn, w1b, hb, nullptr, NROWS, DFF, DM);
  // FFN2 + residual -> d_out: 128x128, BK=64
  k_gemm_nt<1, 128, 64><<<dim3(DM / 128, NROWS / 128), dim3(256), 0, stream>>>(
      hb, w2b, (float*)d_out, yb, NROWS, DM, DFF);
}

// Round 19
// 377.838 us; speedup vs baseline: 1.0064x; 1.0064x over previous
//
#include <hip/hip_runtime.h>

#define DM    1024
#define DFF   4096
#define SEQ   2048
#define BATCH 4
#define NROWS (BATCH * SEQ)   // 8192
#define HEADS 16
#define DKH   64
#define KSTR  (2 * DM)        // fused QK row stride

typedef __attribute__((ext_vector_type(4))) float          f32x4;
typedef __attribute__((ext_vector_type(8))) __bf16         bf16x8;
typedef __attribute__((ext_vector_type(8))) unsigned short u16x8;
typedef __attribute__((ext_vector_type(4))) unsigned short u16x4;

static __device__ __forceinline__ unsigned short f2bf(float f) {
  unsigned u = __builtin_bit_cast(unsigned, f);
  u += 0x7fffu + ((u >> 16) & 1u);   // round-to-nearest-even
  return (unsigned short)(u >> 16);
}

// ---------------- fp32 -> bf16 weight conversion (all 6 tensors, 1 launch) ----------------
struct CvtJobs {
  const float* src[6];
  unsigned short* dst[6];
};
// segment sizes in float4 units: wq,wk,wv,wo = 262144 f4 each, w1,w2 = 1048576 f4.
__constant__ const unsigned c_cum[6] = {262144u, 524288u, 786432u, 1048576u, 2097152u, 3145728u};

__global__ __launch_bounds__(256) void k_f2bf_all(CvtJobs jobs) {
  unsigned i = blockIdx.x * blockDim.x + threadIdx.x;
  if (i >= 3145728u) return;
  int j = 0;
#pragma unroll
  for (int s = 0; s < 6; ++s) j += (i >= c_cum[s]) ? 1 : 0;
  const unsigned base = (j == 0) ? 0u : c_cum[j - 1];
  const unsigned loc  = i - base;
  float4 v = reinterpret_cast<const float4*>(jobs.src[j])[loc];
  ushort4 o;
  o.x = f2bf(v.x); o.y = f2bf(v.y); o.z = f2bf(v.z); o.w = f2bf(v.w);
  reinterpret_cast<ushort4*>(jobs.dst[j])[loc] = o;
}

// ---------------- RMSNorm: fp32 in -> bf16 out ----------------
__global__ __launch_bounds__(256) void k_rmsnorm(const float* __restrict__ x,
                                                 const float* __restrict__ w,
                                                 unsigned short* __restrict__ out) {
  const int row = blockIdx.x;
  const float4 v = reinterpret_cast<const float4*>(x + (size_t)row * DM)[threadIdx.x];
  float ss = v.x * v.x + v.y * v.y + v.z * v.z + v.w * v.w;
#pragma unroll
  for (int off = 32; off > 0; off >>= 1) ss += __shfl_down(ss, off);
  __shared__ float red[4];
  if ((threadIdx.x & 63) == 0) red[threadIdx.x >> 6] = ss;
  __syncthreads();
  const float tot  = red[0] + red[1] + red[2] + red[3];
  const float rden = rsqrtf(tot * (1.0f / DM) + 1e-5f);
  const float4 wv = reinterpret_cast<const float4*>(w)[threadIdx.x];
  ushort4 o;
  o.x = f2bf(v.x * wv.x * rden);
  o.y = f2bf(v.y * wv.y * rden);
  o.z = f2bf(v.z * wv.z * rden);
  o.w = f2bf(v.w * wv.w * rden);
  reinterpret_cast<ushort4*>(out + (size_t)row * DM)[threadIdx.x] = o;
}

// ---------------- NT GEMM: C(MxN) = A(MxK,bf16) * B(NxK,bf16)^T ----------------
// Round-9-proven structure, templated on tile width TN (128/256) and K-step
// BK (32/64). 128xTN tile, 4 waves (2x2); double-buffered 2-phase K-loop;
// row-major LDS with COALESCED staging + granule XOR.
// r10 lesson: never trade staging coalescing for LDS-conflict-freedom.
// r13: TN=256 (only when grid >= 2 blocks/CU). r16: BK=64 for TN=128
// instances (barrier-stall bound; halves barriers/FLOP; per-kk fragment
// loads keep VGPR under the 2-wave cap -- r14 spill lesson).
// EPI: 0 bf16, 1 fp32+res, 2 gelu, 3 Q-prescale.
template <int EPI, int TN, int BK>
__global__ __launch_bounds__(256, 2) void k_gemm_nt(const unsigned short* __restrict__ A,
                                                    const unsigned short* __restrict__ B,
                                                    void* __restrict__ Cv,
                                                    const float* __restrict__ res,
                                                    int M, int N, int K) {
  constexpr int NW = TN / 128;            // B-tile row multiple
  alignas(16) __shared__ unsigned short As[2][128 * BK];
  alignas(16) __shared__ unsigned short Bs[2][128 * NW * BK];
  const int t  = threadIdx.x;
  const int w  = t >> 6;
  const int l  = t & 63;
  const int wr = w >> 1, wc = w & 1;
  const int lr = l & 15, lk = l >> 4;

  const unsigned bid = blockIdx.y * gridDim.x + blockIdx.x;
  const unsigned cpx = (gridDim.x * gridDim.y) >> 3;
  const unsigned sw  = (bid & 7) * cpx + (bid >> 3);
  const int m0 = (int)(sw / gridDim.x) * 128;
  const int n0 = (int)(sw % gridDim.x) * TN;

  auto stage = [&](int buf, int k0) {
    if constexpr (BK == 32) {
      const int srow = t >> 2;                  // 0..63, 4 lanes per 64B row
      const int sgr  = (t & 3) ^ (srow & 3);    // pre-swizzled source granule
#pragma unroll
      for (int r = 0; r < 2; ++r) {
        const unsigned short* ga = A + (size_t)(m0 + r * 64 + srow) * K + k0 + 8 * sgr;
        __builtin_amdgcn_global_load_lds((__attribute__((address_space(1))) void*)ga,
                                         (__attribute__((address_space(3))) void*)(&As[buf][r * 2048 + w * 512]),
                                         16, 0, 0);
      }
#pragma unroll
      for (int r = 0; r < 2 * NW; ++r) {
        const unsigned short* gb = B + (size_t)(n0 + r * 64 + srow) * K + k0 + 8 * sgr;
        __builtin_amdgcn_global_load_lds((__attribute__((address_space(1))) void*)gb,
                                         (__attribute__((address_space(3))) void*)(&Bs[buf][r * 2048 + w * 512]),
                                         16, 0, 0);
      }
    } else {
      // BK == 64 (TN==128): 128B rows, 8 lanes per row; 4 issues cover 128 rows
      const int srow8 = l >> 3;                 // row within wave's 8-row group
      const int g     = l & 7;
#pragma unroll
      for (int i = 0; i < 4; ++i) {
        const int row = i * 32 + w * 8 + srow8;
        const int sg  = g ^ (row & 7);          // pre-swizzled source granule
        const unsigned short* ga = A + (size_t)(m0 + row) * K + k0 + 8 * sg;
        __builtin_amdgcn_global_load_lds((__attribute__((address_space(1))) void*)ga,
                                         (__attribute__((address_space(3))) void*)(&As[buf][i * 2048 + w * 512]),
                                         16, 0, 0);
        const unsigned short* gb = B + (size_t)(n0 + row) * K + k0 + 8 * sg;
        __builtin_amdgcn_global_load_lds((__attribute__((address_space(1))) void*)gb,
                                         (__attribute__((address_space(3))) void*)(&Bs[buf][i * 2048 + w * 512]),
                                         16, 0, 0);
      }
    }
  };

  f32x4 acc[4][4 * NW] = {};

  stage(0, 0);
  const int nIt = K / BK;
  for (int it = 0; it < nIt; ++it) {
    const int buf = it & 1;
    __syncthreads();                          // drains vmcnt -> buf ready; WAR-safe
    if (it + 1 < nIt) stage(buf ^ 1, (it + 1) * BK);

    if constexpr (BK == 32) {
      bf16x8 af[4], bf[4 * NW];
#pragma unroll
      for (int m = 0; m < 4; ++m)
        af[m] = *reinterpret_cast<const bf16x8*>(
            &As[buf][(wr * 64 + m * 16 + lr) * 32 + 8 * (lk ^ (lr & 3))]);
#pragma unroll
      for (int n = 0; n < 4 * NW; ++n)
        bf[n] = *reinterpret_cast<const bf16x8*>(
            &Bs[buf][(wc * 64 * NW + n * 16 + lr) * 32 + 8 * (lk ^ (lr & 3))]);
#pragma unroll
      for (int m = 0; m < 4; ++m)
#pragma unroll
        for (int n = 0; n < 4 * NW; ++n)
          acc[m][n] = __builtin_amdgcn_mfma_f32_16x16x32_bf16(af[m], bf[n], acc[m][n], 0, 0, 0);
    } else {
      // BK == 64: two K=32 slices; load fragments per-slice to bound VGPR
#pragma unroll
      for (int kk = 0; kk < 2; ++kk) {
        bf16x8 af[4], bf[4];
#pragma unroll
        for (int m = 0; m < 4; ++m)
          af[m] = *reinterpret_cast<const bf16x8*>(
              &As[buf][(wr * 64 + m * 16 + lr) * 64 + 8 * ((4 * kk + lk) ^ (lr & 7))]);
#pragma unroll
        for (int n = 0; n < 4; ++n)
          bf[n] = *reinterpret_cast<const bf16x8*>(
              &Bs[buf][(wc * 64 + n * 16 + lr) * 64 + 8 * ((4 * kk + lk) ^ (lr & 7))]);
#pragma unroll
        for (int m = 0; m < 4; ++m)
#pragma unroll
          for (int n = 0; n < 4; ++n)
            acc[m][n] = __builtin_amdgcn_mfma_f32_16x16x32_bf16(af[m], bf[n], acc[m][n], 0, 0, 0);
      }
    }
  }

#pragma unroll
  for (int m = 0; m < 4; ++m) {
#pragma unroll
    for (int n = 0; n < 4 * NW; ++n) {
#pragma unroll
      for (int r = 0; r < 4; ++r) {
        const size_t row = (size_t)(m0 + wr * 64 + m * 16 + lk * 4 + r);
        const size_t col = (size_t)(n0 + wc * 64 * NW + n * 16 + lr);
        const float a = acc[m][n][r];
        if constexpr (EPI == 0) {
          ((unsigned short*)Cv)[row * N + col] = f2bf(a);
        } else if constexpr (EPI == 1) {
          ((float*)Cv)[row * N + col] = a + res[row * N + col];
        } else if constexpr (EPI == 2) {
          // GELU, tanh/exp2 form: g = h - h/(exp2(h*(a1+b1*h^2))+1)
          const float h2 = a * a;
          const float e  = exp2f(a * (2.30221535f + 0.10295355f * h2));
          const float g  = a - a / (e + 1.0f);
          ((unsigned short*)Cv)[row * N + col] = f2bf(g);
        } else {
          const float sc = (col < DM) ? 0.18033688011f : 1.0f;  // 0.125*log2(e) on Q
          ((unsigned short*)Cv)[row * N + col] = f2bf(a * sc);
        }
      }
    }
  }
}

// ---------------- Flash causal attention (64-row folded q-pairs, KVBLK=128) ----------------
// r13/r17 compute structure. ROUND-19: each staged tile now covers 128 keys
// (Ks [128 k][64 dk], Vt [64 d][128 k]), consumed as TWO sequential 64-key
// halves reusing the proven per-64-key code (kb = kbase + 64*h2). Registers
// unchanged (sacc[2][4] -- no r14 spill risk); barrier pairs and stage
// batches halve (the measured serial overhead; r18 showed occupancy/LDS is
// NOT the limit). V rows are 256B -> 16-granule XOR swizzle g^(row&15)
// (write/read symmetric); K rows stay 128B / 8-granule g^(row&7).
// Tree-reduced softmax, setprio on MFMA, Q pre-scaled, defer-max, XCD-grouped.
__global__ __launch_bounds__(256, 3) void k_attn(const unsigned short* __restrict__ QK,
                                                 const unsigned short* __restrict__ VT,
                                                 unsigned short* __restrict__ O) {
  const int h   = blockIdx.x;
  const int qtA = blockIdx.y;                 // 0..15
  const int qtB = 31 - qtA;                   // 31..16
  const int b   = blockIdx.z;
  const int t  = threadIdx.x, w = t >> 6, l = t & 63;
  const int lr = l & 15, lk = l >> 4;
  const size_t rowB = (size_t)b * SEQ;
  const int hoff  = h * DKH;
  const int qw2[2] = { qtA * 64 + 16 * w, qtB * 64 + 16 * w };

  alignas(16) __shared__ unsigned short Ks[128 * 64];      // 16 KB  [k][dk]
  alignas(16) __shared__ unsigned short Vt[64 * 128];      // 16 KB  [d][k]
  alignas(16) __shared__ unsigned short Ps[2][4][16 * 64]; // 16 KB

  char* const KsB = (char*)Ks;
  char* const VtB = (char*)Vt;

  auto stage = [&](int kb2) {
#pragma unroll
    for (int i = 0; i < 4; ++i) {
      // K: wave w covers k-rows 32w..32w+31; issue i = 8 rows x 128B = 1KB
      const int krow = 32 * w + 8 * i + (l >> 3);
      const int sgk  = (l & 7) ^ (krow & 7);
      const unsigned short* gk = QK + (size_t)(rowB + kb2 + krow) * KSTR + DM + hoff + 8 * sgk;
      __builtin_amdgcn_global_load_lds((__attribute__((address_space(1))) void*)gk,
                                       (__attribute__((address_space(3))) void*)(KsB + w * 4096 + i * 1024),
                                       16, 0, 0);
      // V^T: wave w covers d-rows 16w..16w+15; issue i = 4 rows x 256B = 1KB
      const int vrow = 16 * w + 4 * i + (l >> 4);
      const int sgv  = (l & 15) ^ (vrow & 15);
      const unsigned short* gv = VT + (size_t)(hoff + vrow) * NROWS + rowB + kb2 + 8 * sgv;
      __builtin_amdgcn_global_load_lds((__attribute__((address_space(1))) void*)gv,
                                       (__attribute__((address_space(3))) void*)(VtB + w * 4096 + i * 1024),
                                       16, 0, 0);
    }
  };

  bf16x8 qf[2][2];
#pragma unroll
  for (int s = 0; s < 2; ++s)
#pragma unroll
    for (int kk = 0; kk < 2; ++kk)
      qf[s][kk] = *reinterpret_cast<const bf16x8*>(
          QK + (rowB + qw2[s] + lr) * KSTR + hoff + 32 * kk + 8 * lk);

  f32x4 oacc[2][4] = {};
  float mrun[2] = {-1e30f, -1e30f};
  float lrun[2] = {0.0f, 0.0f};

  const int ktmax = qtB >> 1;                 // 128-key tiles
  for (int kt = 0; kt <= ktmax; ++kt) {
    const int kbase = kt * 128;
    __syncthreads();                 // WAR: previous tile's LDS reads complete
    stage(kbase);
    __syncthreads();                 // vmcnt drained -> tile visible

#pragma unroll
    for (int h2 = 0; h2 < 2; ++h2) {
      const int kb = kbase + 64 * h2;
      const bool act[2] = { kb <= qw2[0] + 15, kb <= qw2[1] + 15 };
      if (!act[0] && !act[1]) continue;
      const char* Kc = KsB + h2 * 8192;       // rows 64*h2.. (64*h2&7 == 0)

      f32x4 sacc[2][4] = {};
      __builtin_amdgcn_s_setprio(1);
#pragma unroll
      for (int tt = 0; tt < 4; ++tt) {
        bf16x8 kf0 = *reinterpret_cast<const bf16x8*>(Kc + (16 * tt + lr) * 128 + 16 * ((lk + 0) ^ (lr & 7)));
        bf16x8 kf1 = *reinterpret_cast<const bf16x8*>(Kc + (16 * tt + lr) * 128 + 16 * ((lk + 4) ^ (lr & 7)));
#pragma unroll
        for (int s = 0; s < 2; ++s) {
          if (!act[s]) continue;
          sacc[s][tt] = __builtin_amdgcn_mfma_f32_16x16x32_bf16(kf0, qf[s][0], sacc[s][tt], 0, 0, 0);
          sacc[s][tt] = __builtin_amdgcn_mfma_f32_16x16x32_bf16(kf1, qf[s][1], sacc[s][tt], 0, 0, 0);
        }
      }
      __builtin_amdgcn_s_setprio(0);

#pragma unroll
      for (int s = 0; s < 2; ++s) {
        if (!act[s]) continue;
        const int qw = qw2[s];
        char* const PsSB = (char*)(Ps[s][w]);
        const int qg = qw + lr;
        float sv[4][4];
        if (kb + 63 > qw) {
#pragma unroll
          for (int tt = 0; tt < 4; ++tt)
#pragma unroll
            for (int r = 0; r < 4; ++r) {
              const int kg = kb + 16 * tt + 4 * lk + r;
              sv[tt][r] = (kg > qg) ? -1e30f : sacc[s][tt][r];
            }
        } else {
#pragma unroll
          for (int tt = 0; tt < 4; ++tt)
#pragma unroll
            for (int r = 0; r < 4; ++r) sv[tt][r] = sacc[s][tt][r];
        }
        // fmax tree (depth 3; nested triples fuse to v_max3_f32)
        const float a0 = fmaxf(fmaxf(sv[0][0], sv[0][1]), sv[0][2]);
        const float a1 = fmaxf(fmaxf(sv[0][3], sv[1][0]), sv[1][1]);
        const float a2 = fmaxf(fmaxf(sv[1][2], sv[1][3]), sv[2][0]);
        const float a3 = fmaxf(fmaxf(sv[2][1], sv[2][2]), sv[2][3]);
        const float a4 = fmaxf(fmaxf(sv[3][0], sv[3][1]), sv[3][2]);
        float tm = fmaxf(fmaxf(fmaxf(a0, a1), a2), fmaxf(fmaxf(a3, a4), sv[3][3]));
        tm = fmaxf(tm, __shfl_xor(tm, 16));
        tm = fmaxf(tm, __shfl_xor(tm, 32));
        float mref = mrun[s];
        if (__any(tm > mref + 8.0f)) {            // defer-max
          const float mnew  = fmaxf(mref, tm);
          const float alpha = exp2f(mref - mnew);
#pragma unroll
          for (int r = 0; r < 4; ++r) {
            const float ar = __shfl(alpha, 4 * lk + r);
#pragma unroll
            for (int dn = 0; dn < 4; ++dn) oacc[s][dn][r] *= ar;
          }
          lrun[s] *= alpha;
          mrun[s] = mnew;
          mref = mnew;
        }
        float p[4][4];
        unsigned short pb[4][4];
#pragma unroll
        for (int tt = 0; tt < 4; ++tt)
#pragma unroll
          for (int r = 0; r < 4; ++r) {
            p[tt][r] = exp2f(sv[tt][r] - mref);   // bounded by 2^8
            pb[tt][r] = __builtin_bit_cast(unsigned short, static_cast<__bf16>(p[tt][r]));
          }
        // pairwise sum tree (depth 4)
        float t0 = (p[0][0] + p[0][1]) + (p[0][2] + p[0][3]);
        float t1 = (p[1][0] + p[1][1]) + (p[1][2] + p[1][3]);
        float t2 = (p[2][0] + p[2][1]) + (p[2][2] + p[2][3]);
        float t3 = (p[3][0] + p[3][1]) + (p[3][2] + p[3][3]);
        float ts = (t0 + t1) + (t2 + t3);
        ts += __shfl_xor(ts, 16);
        ts += __shfl_xor(ts, 32);
        lrun[s] += ts;
#pragma unroll
        for (int tt = 0; tt < 4; ++tt) {
          u16x4 pw = {pb[tt][0], pb[tt][1], pb[tt][2], pb[tt][3]};
          *reinterpret_cast<u16x4*>(
              PsSB + lr * 128 + ((32 * tt + 8 * lk) ^ (16 * (lr & 7)))) = pw;
        }
      }

      // order P stores before the TBAA-distinct typed re-reads below
      asm volatile("" ::: "memory");

#pragma unroll
      for (int kk = 0; kk < 2; ++kk) {
        bf16x8 vf[4];
#pragma unroll
        for (int dn = 0; dn < 4; ++dn)
          vf[dn] = *reinterpret_cast<const bf16x8*>(
              VtB + (16 * dn + lr) * 256 + 16 * ((8 * h2 + 4 * kk + lk) ^ lr));
        __builtin_amdgcn_s_setprio(1);
#pragma unroll
        for (int s = 0; s < 2; ++s) {
          if (!act[s]) continue;
          char* const PsSB = (char*)(Ps[s][w]);
          bf16x8 pa = *reinterpret_cast<const bf16x8*>(
              PsSB + lr * 128 + ((64 * kk + 16 * lk) ^ (16 * (lr & 7))));
#pragma unroll
          for (int dn = 0; dn < 4; ++dn)
            oacc[s][dn] = __builtin_amdgcn_mfma_f32_16x16x32_bf16(pa, vf[dn], oacc[s][dn], 0, 0, 0);
        }
        __builtin_amdgcn_s_setprio(0);
      }

      // order PV's P reads before next subtile's P stores (same-wave WAR on Ps)
      asm volatile("" ::: "memory");
    }
  }

#pragma unroll
  for (int s = 0; s < 2; ++s)
#pragma unroll
    for (int r = 0; r < 4; ++r) {
      const float li = 1.0f / __shfl(lrun[s], 4 * lk + r);
      const size_t row = rowB + qw2[s] + 4 * lk + r;
#pragma unroll
      for (int dn = 0; dn < 4; ++dn)
        O[row * DM + hoff + 16 * dn + lr] = f2bf(oacc[s][dn][r] * li);
    }
}

// ---------------- launch ----------------
extern "C" void kernel_launch(void* const* d_in, const int* in_sizes, int n_in,
                              void* d_out, int out_size, void* d_ws, size_t ws_size,
                              hipStream_t stream) {
  const float* x   = (const float*)d_in[0];
  const float* ln1 = (const float*)d_in[1];
  const float* ln2 = (const float*)d_in[2];
  const float* wq  = (const float*)d_in[3];
  const float* wk  = (const float*)d_in[4];
  const float* wv  = (const float*)d_in[5];
  const float* wo  = (const float*)d_in[6];
  const float* w1  = (const float*)d_in[7];
  const float* w2  = (const float*)d_in[8];

  char* ws = (char*)d_ws;
  size_t off = 0;
  auto take = [&](size_t bytes) { void* p = ws + off; off += bytes; return p; };
  unsigned short* wqkb = (unsigned short*)take((size_t)2 * DM * DM * 2);   // 4 MB (Q,K fused)
  unsigned short* wvb  = (unsigned short*)take((size_t)DM * DM * 2);       // 2 MB
  unsigned short* wob  = (unsigned short*)take((size_t)DM * DM * 2);       // 2 MB
  unsigned short* w1b  = (unsigned short*)take((size_t)DFF * DM * 2);      // 8 MB
  unsigned short* w2b  = (unsigned short*)take((size_t)DM * DFF * 2);      // 8 MB
  unsigned short* qk   = (unsigned short*)take((size_t)NROWS * 2 * DM * 2); // 32 MB
  unsigned short* xn   = (unsigned short*)take((size_t)NROWS * DM * 2);    // 16 MB (ln1 out, reused attn-out)
  unsigned short* vtb  = (unsigned short*)take((size_t)DM * NROWS * 2);    // 16 MB V^T [DM][NROWS]
  float*          yb   = (float*)take((size_t)NROWS * DM * 4);             // 32 MB fp32 residual
  unsigned short* hb   = (unsigned short*)take((size_t)NROWS * DFF * 2);   // 64 MB
  unsigned short* yn   = qk;   // ln2 out aliases qk (dead after attn)

  // one fused weight-conversion dispatch (segment order matches c_cum)
  CvtJobs jobs;
  jobs.src[0] = wq;  jobs.dst[0] = wqkb;
  jobs.src[1] = wk;  jobs.dst[1] = wqkb + (size_t)DM * DM;
  jobs.src[2] = wv;  jobs.dst[2] = wvb;
  jobs.src[3] = wo;  jobs.dst[3] = wob;
  jobs.src[4] = w1;  jobs.dst[4] = w1b;
  jobs.src[5] = w2;  jobs.dst[5] = w2b;
  k_f2bf_all<<<dim3(3145728u / 256u), dim3(256), 0, stream>>>(jobs);

  k_rmsnorm<<<dim3(NROWS), dim3(256), 0, stream>>>(x, ln1, xn);

  // fused QK projection (EPI3: Q columns pre-scaled), 128x256 tile, BK=32
  k_gemm_nt<3, 256, 32><<<dim3(2 * DM / 256, NROWS / 128), dim3(256), 0, stream>>>(
      xn, wqkb, qk, nullptr, NROWS, 2 * DM, DM);

  // V^T directly: VT[DM][NROWS] = wv @ xn^T (operands swapped), 128x128, BK=64
  k_gemm_nt<0, 128, 64><<<dim3(NROWS / 128, DM / 128), dim3(256), 0, stream>>>(
      wvb, xn, vtb, nullptr, DM, NROWS, DM);

  k_attn<<<dim3(HEADS, 16, BATCH), dim3(256), 0, stream>>>(qk, vtb, xn);

  // WO projection + residual: 128x128, BK=64
  k_gemm_nt<1, 128, 64><<<dim3(DM / 128, NROWS / 128), dim3(256), 0, stream>>>(
      xn, wob, yb, x, NROWS, DM, DM);

  k_rmsnorm<<<dim3(NROWS), dim3(256), 0, stream>>>(yb, ln2, yn);

  // FFN1: 128x256 tile, BK=32 (grid 16x64 = 1024 blocks)
  k_gemm_nt<2, 256, 32><<<dim3(DFF / 256, NROWS / 128), dim3(256), 0, stream>>>(
      yn, w1b, hb, nullptr, NROWS, DFF, DM);
  // FFN2 + residual -> d_out: 128x128, BK=64
  k_gemm_nt<1, 128, 64><<<dim3(DM / 128, NROWS / 128), dim3(256), 0, stream>>>(
      hb, w2b, (float*)d_out, yb, NROWS, DM, DFF);
}

// Round 20
// 373.296 us; speedup vs baseline: 1.0186x; 1.0122x over previous
//
#include <hip/hip_runtime.h>

#define DM    1024
#define DFF   4096
#define SEQ   2048
#define BATCH 4
#define NROWS (BATCH * SEQ)   // 8192
#define HEADS 16
#define DKH   64
#define KSTR  (2 * DM)        // fused QK row stride

typedef __attribute__((ext_vector_type(4))) float          f32x4;
typedef __attribute__((ext_vector_type(8))) __bf16         bf16x8;
typedef __attribute__((ext_vector_type(8))) unsigned short u16x8;
typedef __attribute__((ext_vector_type(4))) unsigned short u16x4;

static __device__ __forceinline__ unsigned short f2bf(float f) {
  unsigned u = __builtin_bit_cast(unsigned, f);
  u += 0x7fffu + ((u >> 16) & 1u);   // round-to-nearest-even
  return (unsigned short)(u >> 16);
}

// ---------------- fused prologue: weight f2bf (6 tensors) + RMSNorm1 ----------------
struct CvtJobs {
  const float* src[6];
  unsigned short* dst[6];
};
// segment sizes in float4 units: wq,wk,wv,wo = 262144 f4 each, w1,w2 = 1048576 f4.
__constant__ const unsigned c_cum[6] = {262144u, 524288u, 786432u, 1048576u, 2097152u, 3145728u};
#define CVT_BLOCKS 12288u   // 3145728 / 256

__global__ __launch_bounds__(256) void k_pre(CvtJobs jobs,
                                             const float* __restrict__ x,
                                             const float* __restrict__ ln1,
                                             unsigned short* __restrict__ xn) {
  if (blockIdx.x < CVT_BLOCKS) {
    const unsigned i = blockIdx.x * 256u + threadIdx.x;   // < 3145728 exactly
    int j = 0;
#pragma unroll
    for (int s = 0; s < 6; ++s) j += (i >= c_cum[s]) ? 1 : 0;
    const unsigned base = (j == 0) ? 0u : c_cum[j - 1];
    const unsigned loc  = i - base;
    float4 v = reinterpret_cast<const float4*>(jobs.src[j])[loc];
    ushort4 o;
    o.x = f2bf(v.x); o.y = f2bf(v.y); o.z = f2bf(v.z); o.w = f2bf(v.w);
    reinterpret_cast<ushort4*>(jobs.dst[j])[loc] = o;
  } else {
    const int row = (int)(blockIdx.x - CVT_BLOCKS);
    const float4 v = reinterpret_cast<const float4*>(x + (size_t)row * DM)[threadIdx.x];
    float ss = v.x * v.x + v.y * v.y + v.z * v.z + v.w * v.w;
#pragma unroll
    for (int off = 32; off > 0; off >>= 1) ss += __shfl_down(ss, off);
    __shared__ float red[4];
    if ((threadIdx.x & 63) == 0) red[threadIdx.x >> 6] = ss;
    __syncthreads();
    const float tot  = red[0] + red[1] + red[2] + red[3];
    const float rden = rsqrtf(tot * (1.0f / DM) + 1e-5f);
    const float4 wv = reinterpret_cast<const float4*>(ln1)[threadIdx.x];
    ushort4 o;
    o.x = f2bf(v.x * wv.x * rden);
    o.y = f2bf(v.y * wv.y * rden);
    o.z = f2bf(v.z * wv.z * rden);
    o.w = f2bf(v.w * wv.w * rden);
    reinterpret_cast<ushort4*>(xn + (size_t)row * DM)[threadIdx.x] = o;
  }
}

// ---------------- RMSNorm: fp32 in -> bf16 out (ln2, standalone) ----------------
__global__ __launch_bounds__(256) void k_rmsnorm(const float* __restrict__ x,
                                                 const float* __restrict__ w,
                                                 unsigned short* __restrict__ out) {
  const int row = blockIdx.x;
  const float4 v = reinterpret_cast<const float4*>(x + (size_t)row * DM)[threadIdx.x];
  float ss = v.x * v.x + v.y * v.y + v.z * v.z + v.w * v.w;
#pragma unroll
  for (int off = 32; off > 0; off >>= 1) ss += __shfl_down(ss, off);
  __shared__ float red[4];
  if ((threadIdx.x & 63) == 0) red[threadIdx.x >> 6] = ss;
  __syncthreads();
  const float tot  = red[0] + red[1] + red[2] + red[3];
  const float rden = rsqrtf(tot * (1.0f / DM) + 1e-5f);
  const float4 wv = reinterpret_cast<const float4*>(w)[threadIdx.x];
  ushort4 o;
  o.x = f2bf(v.x * wv.x * rden);
  o.y = f2bf(v.y * wv.y * rden);
  o.z = f2bf(v.z * wv.z * rden);
  o.w = f2bf(v.w * wv.w * rden);
  reinterpret_cast<ushort4*>(out + (size_t)row * DM)[threadIdx.x] = o;
}

// ---------------- shared GEMM body: 128x128 tile, BK=64 (r16-proven path) ----------------
// Virtualized (vbid, vgx, vgy) so multiple GEMMs can share one dispatch.
// Row-major LDS, coalesced staging (8 lanes per 128B row) + granule XOR,
// double-buffered 2-phase K-loop, per-kk fragment loads (r14 spill lesson).
// Epilogue: bf16 store; if prescale, cols < DM scaled by 0.125*log2e.
__device__ __forceinline__ void gemm_body_128_64(const unsigned short* __restrict__ A,
                                                 const unsigned short* __restrict__ B,
                                                 unsigned short* __restrict__ C,
                                                 int M, int N, int K, bool prescale,
                                                 unsigned vbid, unsigned vgx, unsigned vgy,
                                                 unsigned short* AsP, unsigned short* BsP) {
  const int t  = threadIdx.x;
  const int w  = t >> 6;
  const int l  = t & 63;
  const int wr = w >> 1, wc = w & 1;
  const int lr = l & 15, lk = l >> 4;

  const unsigned cpx = (vgx * vgy) >> 3;
  const unsigned sw  = (vbid & 7) * cpx + (vbid >> 3);
  const int m0 = (int)(sw / vgx) * 128;
  const int n0 = (int)(sw % vgx) * 128;

  const int srow8 = l >> 3;
  const int g     = l & 7;

  auto stage = [&](int buf, int k0) {
#pragma unroll
    for (int i = 0; i < 4; ++i) {
      const int row = i * 32 + w * 8 + srow8;
      const int sg  = g ^ (row & 7);
      const unsigned short* ga = A + (size_t)(m0 + row) * K + k0 + 8 * sg;
      __builtin_amdgcn_global_load_lds((__attribute__((address_space(1))) void*)ga,
                                       (__attribute__((address_space(3))) void*)(AsP + buf * 8192 + i * 2048 + w * 512),
                                       16, 0, 0);
      const unsigned short* gb = B + (size_t)(n0 + row) * K + k0 + 8 * sg;
      __builtin_amdgcn_global_load_lds((__attribute__((address_space(1))) void*)gb,
                                       (__attribute__((address_space(3))) void*)(BsP + buf * 8192 + i * 2048 + w * 512),
                                       16, 0, 0);
    }
  };

  f32x4 acc[4][4] = {};

  stage(0, 0);
  const int nIt = K >> 6;
  for (int it = 0; it < nIt; ++it) {
    const int buf = it & 1;
    __syncthreads();                          // drains vmcnt -> buf ready; WAR-safe
    if (it + 1 < nIt) stage(buf ^ 1, (it + 1) << 6);

#pragma unroll
    for (int kk = 0; kk < 2; ++kk) {
      bf16x8 af[4], bf[4];
#pragma unroll
      for (int m = 0; m < 4; ++m)
        af[m] = *reinterpret_cast<const bf16x8*>(
            AsP + buf * 8192 + (wr * 64 + m * 16 + lr) * 64 + 8 * ((4 * kk + lk) ^ (lr & 7)));
#pragma unroll
      for (int n = 0; n < 4; ++n)
        bf[n] = *reinterpret_cast<const bf16x8*>(
            BsP + buf * 8192 + (wc * 64 + n * 16 + lr) * 64 + 8 * ((4 * kk + lk) ^ (lr & 7)));
#pragma unroll
      for (int m = 0; m < 4; ++m)
#pragma unroll
        for (int n = 0; n < 4; ++n)
          acc[m][n] = __builtin_amdgcn_mfma_f32_16x16x32_bf16(af[m], bf[n], acc[m][n], 0, 0, 0);
    }
  }

#pragma unroll
  for (int m = 0; m < 4; ++m) {
#pragma unroll
    for (int n = 0; n < 4; ++n) {
#pragma unroll
      for (int r = 0; r < 4; ++r) {
        const size_t row = (size_t)(m0 + wr * 64 + m * 16 + lk * 4 + r);
        const size_t col = (size_t)(n0 + wc * 64 + n * 16 + lr);
        const float sc = (prescale && col < DM) ? 0.18033688011f : 1.0f;  // 0.125*log2(e)
        C[row * N + col] = f2bf(acc[m][n][r] * sc);
      }
    }
  }
}

// ---------------- fused QK-projection + V^T GEMM (one dispatch, 1536 blocks) ----------------
// Blocks 0..1023: qk[8192x2048] = xn @ wqk^T (Q cols pre-scaled), virtual grid 16x64.
// Blocks 1024..1535: vtb[1024x8192] = wv @ xn^T, virtual grid 64x8.
// Both are independent consumers of xn; fusing overlaps the second GEMM with the
// first one's tail and removes a launch gap. Bodies are the r16-proven path.
__global__ __launch_bounds__(256, 2) void k_qkvt(const unsigned short* __restrict__ xn,
                                                 const unsigned short* __restrict__ wqkb,
                                                 unsigned short* __restrict__ qk,
                                                 const unsigned short* __restrict__ wvb,
                                                 unsigned short* __restrict__ vtb) {
  alignas(16) __shared__ unsigned short As[2][128 * 64];
  alignas(16) __shared__ unsigned short Bs[2][128 * 64];
  const unsigned bid = blockIdx.x;
  if (bid < 1024u) {
    gemm_body_128_64(xn, wqkb, qk, NROWS, 2 * DM, DM, true, bid, 16, 64, &As[0][0], &Bs[0][0]);
  } else {
    gemm_body_128_64(wvb, xn, vtb, DM, NROWS, DM, false, bid - 1024u, 64, 8, &As[0][0], &Bs[0][0]);
  }
}

// ---------------- NT GEMM: C(MxN) = A(MxK,bf16) * B(NxK,bf16)^T ----------------
// r9-proven structure, templated on TN (128/256) and BK (32/64).
// r10: never trade staging coalescing for LDS-conflict-freedom. r13: TN=256
// only when grid >= 2 blocks/CU. r16: BK=64 for TN=128 (barrier-stall bound).
// EPI: 1 fp32 = acc + res, 2 bf16 gelu.
template <int EPI, int TN, int BK>
__global__ __launch_bounds__(256, 2) void k_gemm_nt(const unsigned short* __restrict__ A,
                                                    const unsigned short* __restrict__ B,
                                                    void* __restrict__ Cv,
                                                    const float* __restrict__ res,
                                                    int M, int N, int K) {
  constexpr int NW = TN / 128;
  alignas(16) __shared__ unsigned short As[2][128 * BK];
  alignas(16) __shared__ unsigned short Bs[2][128 * NW * BK];
  const int t  = threadIdx.x;
  const int w  = t >> 6;
  const int l  = t & 63;
  const int wr = w >> 1, wc = w & 1;
  const int lr = l & 15, lk = l >> 4;

  const unsigned bid = blockIdx.y * gridDim.x + blockIdx.x;
  const unsigned cpx = (gridDim.x * gridDim.y) >> 3;
  const unsigned sw  = (bid & 7) * cpx + (bid >> 3);
  const int m0 = (int)(sw / gridDim.x) * 128;
  const int n0 = (int)(sw % gridDim.x) * TN;

  auto stage = [&](int buf, int k0) {
    if constexpr (BK == 32) {
      const int srow = t >> 2;
      const int sgr  = (t & 3) ^ (srow & 3);
#pragma unroll
      for (int r = 0; r < 2; ++r) {
        const unsigned short* ga = A + (size_t)(m0 + r * 64 + srow) * K + k0 + 8 * sgr;
        __builtin_amdgcn_global_load_lds((__attribute__((address_space(1))) void*)ga,
                                         (__attribute__((address_space(3))) void*)(&As[buf][r * 2048 + w * 512]),
                                         16, 0, 0);
      }
#pragma unroll
      for (int r = 0; r < 2 * NW; ++r) {
        const unsigned short* gb = B + (size_t)(n0 + r * 64 + srow) * K + k0 + 8 * sgr;
        __builtin_amdgcn_global_load_lds((__attribute__((address_space(1))) void*)gb,
                                         (__attribute__((address_space(3))) void*)(&Bs[buf][r * 2048 + w * 512]),
                                         16, 0, 0);
      }
    } else {
      const int srow8 = l >> 3;
      const int g     = l & 7;
#pragma unroll
      for (int i = 0; i < 4; ++i) {
        const int row = i * 32 + w * 8 + srow8;
        const int sg  = g ^ (row & 7);
        const unsigned short* ga = A + (size_t)(m0 + row) * K + k0 + 8 * sg;
        __builtin_amdgcn_global_load_lds((__attribute__((address_space(1))) void*)ga,
                                         (__attribute__((address_space(3))) void*)(&As[buf][i * 2048 + w * 512]),
                                         16, 0, 0);
        const unsigned short* gb = B + (size_t)(n0 + row) * K + k0 + 8 * sg;
        __builtin_amdgcn_global_load_lds((__attribute__((address_space(1))) void*)gb,
                                         (__attribute__((address_space(3))) void*)(&Bs[buf][i * 2048 + w * 512]),
                                         16, 0, 0);
      }
    }
  };

  f32x4 acc[4][4 * NW] = {};

  stage(0, 0);
  const int nIt = K / BK;
  for (int it = 0; it < nIt; ++it) {
    const int buf = it & 1;
    __syncthreads();
    if (it + 1 < nIt) stage(buf ^ 1, (it + 1) * BK);

    if constexpr (BK == 32) {
      bf16x8 af[4], bf[4 * NW];
#pragma unroll
      for (int m = 0; m < 4; ++m)
        af[m] = *reinterpret_cast<const bf16x8*>(
            &As[buf][(wr * 64 + m * 16 + lr) * 32 + 8 * (lk ^ (lr & 3))]);
#pragma unroll
      for (int n = 0; n < 4 * NW; ++n)
        bf[n] = *reinterpret_cast<const bf16x8*>(
            &Bs[buf][(wc * 64 * NW + n * 16 + lr) * 32 + 8 * (lk ^ (lr & 3))]);
#pragma unroll
      for (int m = 0; m < 4; ++m)
#pragma unroll
        for (int n = 0; n < 4 * NW; ++n)
          acc[m][n] = __builtin_amdgcn_mfma_f32_16x16x32_bf16(af[m], bf[n], acc[m][n], 0, 0, 0);
    } else {
#pragma unroll
      for (int kk = 0; kk < 2; ++kk) {
        bf16x8 af[4], bf[4];
#pragma unroll
        for (int m = 0; m < 4; ++m)
          af[m] = *reinterpret_cast<const bf16x8*>(
              &As[buf][(wr * 64 + m * 16 + lr) * 64 + 8 * ((4 * kk + lk) ^ (lr & 7))]);
#pragma unroll
        for (int n = 0; n < 4; ++n)
          bf[n] = *reinterpret_cast<const bf16x8*>(
              &Bs[buf][(wc * 64 + n * 16 + lr) * 64 + 8 * ((4 * kk + lk) ^ (lr & 7))]);
#pragma unroll
        for (int m = 0; m < 4; ++m)
#pragma unroll
          for (int n = 0; n < 4; ++n)
            acc[m][n] = __builtin_amdgcn_mfma_f32_16x16x32_bf16(af[m], bf[n], acc[m][n], 0, 0, 0);
      }
    }
  }

#pragma unroll
  for (int m = 0; m < 4; ++m) {
#pragma unroll
    for (int n = 0; n < 4 * NW; ++n) {
#pragma unroll
      for (int r = 0; r < 4; ++r) {
        const size_t row = (size_t)(m0 + wr * 64 + m * 16 + lk * 4 + r);
        const size_t col = (size_t)(n0 + wc * 64 * NW + n * 16 + lr);
        const float a = acc[m][n][r];
        if constexpr (EPI == 1) {
          ((float*)Cv)[row * N + col] = a + res[row * N + col];
        } else {
          // GELU, tanh/exp2 form
          const float h2 = a * a;
          const float e  = exp2f(a * (2.30221535f + 0.10295355f * h2));
          const float g  = a - a / (e + 1.0f);
          ((unsigned short*)Cv)[row * N + col] = f2bf(g);
        }
      }
    }
  }
}

// ---------------- Flash causal attention (64-row folded q-pairs, KVBLK=128) ----------------
// r19 version: staged tiles cover 128 keys consumed as two 64-key halves;
// tree-reduced softmax, setprio on MFMA, Q pre-scaled, defer-max, XCD-grouped.
__global__ __launch_bounds__(256, 3) void k_attn(const unsigned short* __restrict__ QK,
                                                 const unsigned short* __restrict__ VT,
                                                 unsigned short* __restrict__ O) {
  const int h   = blockIdx.x;
  const int qtA = blockIdx.y;                 // 0..15
  const int qtB = 31 - qtA;                   // 31..16
  const int b   = blockIdx.z;
  const int t  = threadIdx.x, w = t >> 6, l = t & 63;
  const int lr = l & 15, lk = l >> 4;
  const size_t rowB = (size_t)b * SEQ;
  const int hoff  = h * DKH;
  const int qw2[2] = { qtA * 64 + 16 * w, qtB * 64 + 16 * w };

  alignas(16) __shared__ unsigned short Ks[128 * 64];      // 16 KB  [k][dk]
  alignas(16) __shared__ unsigned short Vt[64 * 128];      // 16 KB  [d][k]
  alignas(16) __shared__ unsigned short Ps[2][4][16 * 64]; // 16 KB

  char* const KsB = (char*)Ks;
  char* const VtB = (char*)Vt;

  auto stage = [&](int kb2) {
#pragma unroll
    for (int i = 0; i < 4; ++i) {
      const int krow = 32 * w + 8 * i + (l >> 3);
      const int sgk  = (l & 7) ^ (krow & 7);
      const unsigned short* gk = QK + (size_t)(rowB + kb2 + krow) * KSTR + DM + hoff + 8 * sgk;
      __builtin_amdgcn_global_load_lds((__attribute__((address_space(1))) void*)gk,
                                       (__attribute__((address_space(3))) void*)(KsB + w * 4096 + i * 1024),
                                       16, 0, 0);
      const int vrow = 16 * w + 4 * i + (l >> 4);
      const int sgv  = (l & 15) ^ (vrow & 15);
      const unsigned short* gv = VT + (size_t)(hoff + vrow) * NROWS + rowB + kb2 + 8 * sgv;
      __builtin_amdgcn_global_load_lds((__attribute__((address_space(1))) void*)gv,
                                       (__attribute__((address_space(3))) void*)(VtB + w * 4096 + i * 1024),
                                       16, 0, 0);
    }
  };

  bf16x8 qf[2][2];
#pragma unroll
  for (int s = 0; s < 2; ++s)
#pragma unroll
    for (int kk = 0; kk < 2; ++kk)
      qf[s][kk] = *reinterpret_cast<const bf16x8*>(
          QK + (rowB + qw2[s] + lr) * KSTR + hoff + 32 * kk + 8 * lk);

  f32x4 oacc[2][4] = {};
  float mrun[2] = {-1e30f, -1e30f};
  float lrun[2] = {0.0f, 0.0f};

  const int ktmax = qtB >> 1;                 // 128-key tiles
  for (int kt = 0; kt <= ktmax; ++kt) {
    const int kbase = kt * 128;
    __syncthreads();
    stage(kbase);
    __syncthreads();

#pragma unroll
    for (int h2 = 0; h2 < 2; ++h2) {
      const int kb = kbase + 64 * h2;
      const bool act[2] = { kb <= qw2[0] + 15, kb <= qw2[1] + 15 };
      if (!act[0] && !act[1]) continue;
      const char* Kc = KsB + h2 * 8192;

      f32x4 sacc[2][4] = {};
      __builtin_amdgcn_s_setprio(1);
#pragma unroll
      for (int tt = 0; tt < 4; ++tt) {
        bf16x8 kf0 = *reinterpret_cast<const bf16x8*>(Kc + (16 * tt + lr) * 128 + 16 * ((lk + 0) ^ (lr & 7)));
        bf16x8 kf1 = *reinterpret_cast<const bf16x8*>(Kc + (16 * tt + lr) * 128 + 16 * ((lk + 4) ^ (lr & 7)));
#pragma unroll
        for (int s = 0; s < 2; ++s) {
          if (!act[s]) continue;
          sacc[s][tt] = __builtin_amdgcn_mfma_f32_16x16x32_bf16(kf0, qf[s][0], sacc[s][tt], 0, 0, 0);
          sacc[s][tt] = __builtin_amdgcn_mfma_f32_16x16x32_bf16(kf1, qf[s][1], sacc[s][tt], 0, 0, 0);
        }
      }
      __builtin_amdgcn_s_setprio(0);

#pragma unroll
      for (int s = 0; s < 2; ++s) {
        if (!act[s]) continue;
        const int qw = qw2[s];
        char* const PsSB = (char*)(Ps[s][w]);
        const int qg = qw + lr;
        float sv[4][4];
        if (kb + 63 > qw) {
#pragma unroll
          for (int tt = 0; tt < 4; ++tt)
#pragma unroll
            for (int r = 0; r < 4; ++r) {
              const int kg = kb + 16 * tt + 4 * lk + r;
              sv[tt][r] = (kg > qg) ? -1e30f : sacc[s][tt][r];
            }
        } else {
#pragma unroll
          for (int tt = 0; tt < 4; ++tt)
#pragma unroll
            for (int r = 0; r < 4; ++r) sv[tt][r] = sacc[s][tt][r];
        }
        const float a0 = fmaxf(fmaxf(sv[0][0], sv[0][1]), sv[0][2]);
        const float a1 = fmaxf(fmaxf(sv[0][3], sv[1][0]), sv[1][1]);
        const float a2 = fmaxf(fmaxf(sv[1][2], sv[1][3]), sv[2][0]);
        const float a3 = fmaxf(fmaxf(sv[2][1], sv[2][2]), sv[2][3]);
        const float a4 = fmaxf(fmaxf(sv[3][0], sv[3][1]), sv[3][2]);
        float tm = fmaxf(fmaxf(fmaxf(a0, a1), a2), fmaxf(fmaxf(a3, a4), sv[3][3]));
        tm = fmaxf(tm, __shfl_xor(tm, 16));
        tm = fmaxf(tm, __shfl_xor(tm, 32));
        float mref = mrun[s];
        if (__any(tm > mref + 8.0f)) {            // defer-max
          const float mnew  = fmaxf(mref, tm);
          const float alpha = exp2f(mref - mnew);
#pragma unroll
          for (int r = 0; r < 4; ++r) {
            const float ar = __shfl(alpha, 4 * lk + r);
#pragma unroll
            for (int dn = 0; dn < 4; ++dn) oacc[s][dn][r] *= ar;
          }
          lrun[s] *= alpha;
          mrun[s] = mnew;
          mref = mnew;
        }
        float p[4][4];
        unsigned short pb[4][4];
#pragma unroll
        for (int tt = 0; tt < 4; ++tt)
#pragma unroll
          for (int r = 0; r < 4; ++r) {
            p[tt][r] = exp2f(sv[tt][r] - mref);
            pb[tt][r] = __builtin_bit_cast(unsigned short, static_cast<__bf16>(p[tt][r]));
          }
        float t0 = (p[0][0] + p[0][1]) + (p[0][2] + p[0][3]);
        float t1 = (p[1][0] + p[1][1]) + (p[1][2] + p[1][3]);
        float t2 = (p[2][0] + p[2][1]) + (p[2][2] + p[2][3]);
        float t3 = (p[3][0] + p[3][1]) + (p[3][2] + p[3][3]);
        float ts = (t0 + t1) + (t2 + t3);
        ts += __shfl_xor(ts, 16);
        ts += __shfl_xor(ts, 32);
        lrun[s] += ts;
#pragma unroll
        for (int tt = 0; tt < 4; ++tt) {
          u16x4 pw = {pb[tt][0], pb[tt][1], pb[tt][2], pb[tt][3]};
          *reinterpret_cast<u16x4*>(
              PsSB + lr * 128 + ((32 * tt + 8 * lk) ^ (16 * (lr & 7)))) = pw;
        }
      }

      asm volatile("" ::: "memory");

#pragma unroll
      for (int kk = 0; kk < 2; ++kk) {
        bf16x8 vf[4];
#pragma unroll
        for (int dn = 0; dn < 4; ++dn)
          vf[dn] = *reinterpret_cast<const bf16x8*>(
              VtB + (16 * dn + lr) * 256 + 16 * ((8 * h2 + 4 * kk + lk) ^ lr));
        __builtin_amdgcn_s_setprio(1);
#pragma unroll
        for (int s = 0; s < 2; ++s) {
          if (!act[s]) continue;
          char* const PsSB = (char*)(Ps[s][w]);
          bf16x8 pa = *reinterpret_cast<const bf16x8*>(
              PsSB + lr * 128 + ((64 * kk + 16 * lk) ^ (16 * (lr & 7))));
#pragma unroll
          for (int dn = 0; dn < 4; ++dn)
            oacc[s][dn] = __builtin_amdgcn_mfma_f32_16x16x32_bf16(pa, vf[dn], oacc[s][dn], 0, 0, 0);
        }
        __builtin_amdgcn_s_setprio(0);
      }

      asm volatile("" ::: "memory");
    }
  }

#pragma unroll
  for (int s = 0; s < 2; ++s)
#pragma unroll
    for (int r = 0; r < 4; ++r) {
      const float li = 1.0f / __shfl(lrun[s], 4 * lk + r);
      const size_t row = rowB + qw2[s] + 4 * lk + r;
#pragma unroll
      for (int dn = 0; dn < 4; ++dn)
        O[row * DM + hoff + 16 * dn + lr] = f2bf(oacc[s][dn][r] * li);
    }
}

// ---------------- launch ----------------
extern "C" void kernel_launch(void* const* d_in, const int* in_sizes, int n_in,
                              void* d_out, int out_size, void* d_ws, size_t ws_size,
                              hipStream_t stream) {
  const float* x   = (const float*)d_in[0];
  const float* ln1 = (const float*)d_in[1];
  const float* ln2 = (const float*)d_in[2];
  const float* wq  = (const float*)d_in[3];
  const float* wk  = (const float*)d_in[4];
  const float* wv  = (const float*)d_in[5];
  const float* wo  = (const float*)d_in[6];
  const float* w1  = (const float*)d_in[7];
  const float* w2  = (const float*)d_in[8];

  char* ws = (char*)d_ws;
  size_t off = 0;
  auto take = [&](size_t bytes) { void* p = ws + off; off += bytes; return p; };
  unsigned short* wqkb = (unsigned short*)take((size_t)2 * DM * DM * 2);   // 4 MB (Q,K fused)
  unsigned short* wvb  = (unsigned short*)take((size_t)DM * DM * 2);       // 2 MB
  unsigned short* wob  = (unsigned short*)take((size_t)DM * DM * 2);       // 2 MB
  unsigned short* w1b  = (unsigned short*)take((size_t)DFF * DM * 2);      // 8 MB
  unsigned short* w2b  = (unsigned short*)take((size_t)DM * DFF * 2);      // 8 MB
  unsigned short* qk   = (unsigned short*)take((size_t)NROWS * 2 * DM * 2); // 32 MB
  unsigned short* xn   = (unsigned short*)take((size_t)NROWS * DM * 2);    // 16 MB (ln1 out, reused attn-out)
  unsigned short* vtb  = (unsigned short*)take((size_t)DM * NROWS * 2);    // 16 MB V^T [DM][NROWS]
  float*          yb   = (float*)take((size_t)NROWS * DM * 4);             // 32 MB fp32 residual
  unsigned short* hb   = (unsigned short*)take((size_t)NROWS * DFF * 2);   // 64 MB
  unsigned short* yn   = qk;   // ln2 out aliases qk (dead after attn)

  CvtJobs jobs;
  jobs.src[0] = wq;  jobs.dst[0] = wqkb;
  jobs.src[1] = wk;  jobs.dst[1] = wqkb + (size_t)DM * DM;
  jobs.src[2] = wv;  jobs.dst[2] = wvb;
  jobs.src[3] = wo;  jobs.dst[3] = wob;
  jobs.src[4] = w1;  jobs.dst[4] = w1b;
  jobs.src[5] = w2;  jobs.dst[5] = w2b;

  // fused prologue: weight conversion + rmsnorm1
  k_pre<<<dim3(CVT_BLOCKS + NROWS), dim3(256), 0, stream>>>(jobs, x, ln1, xn);

  // fused QK projection + V^T GEMM (one dispatch)
  k_qkvt<<<dim3(1536), dim3(256), 0, stream>>>(xn, wqkb, qk, wvb, vtb);

  k_attn<<<dim3(HEADS, 16, BATCH), dim3(256), 0, stream>>>(qk, vtb, xn);

  // WO projection + residual: 128x128, BK=64
  k_gemm_nt<1, 128, 64><<<dim3(DM / 128, NROWS / 128), dim3(256), 0, stream>>>(
      xn, wob, yb, x, NROWS, DM, DM);

  k_rmsnorm<<<dim3(NROWS), dim3(256), 0, stream>>>(yb, ln2, yn);

  // FFN1: 128x256 tile, BK=32 (grid 16x64 = 1024 blocks)
  k_gemm_nt<2, 256, 32><<<dim3(DFF / 256, NROWS / 128), dim3(256), 0, stream>>>(
      yn, w1b, hb, nullptr, NROWS, DFF, DM);
  // FFN2 + residual -> d_out: 128x128, BK=64
  k_gemm_nt<1, 128, 64><<<dim3(DM / 128, NROWS / 128), dim3(256), 0, stream>>>(
      hb, w2b, (float*)d_out, yb, NROWS, DM, DFF);
}

// Round 21
// 369.556 us; speedup vs baseline: 1.0289x; 1.0101x over previous
//
#include <hip/hip_runtime.h>

#define DM    1024
#define DFF   4096
#define SEQ   2048
#define BATCH 4
#define NROWS (BATCH * SEQ)   // 8192
#define HEADS 16
#define DKH   64
#define KSTR  (2 * DM)        // fused QK row stride

typedef __attribute__((ext_vector_type(4))) float          f32x4;
typedef __attribute__((ext_vector_type(8))) __bf16         bf16x8;
typedef __attribute__((ext_vector_type(8))) unsigned short u16x8;
typedef __attribute__((ext_vector_type(4))) unsigned short u16x4;

static __device__ __forceinline__ unsigned short f2bf(float f) {
  unsigned u = __builtin_bit_cast(unsigned, f);
  u += 0x7fffu + ((u >> 16) & 1u);   // round-to-nearest-even
  return (unsigned short)(u >> 16);
}

// ---------------- fused prologue: f2bf(wq,wk,wv) + RMSNorm1 ----------------
// Only the weights needed by k_qkvt are converted here; wo/w1/w2 conversion
// rides inside k_attn's grid (trailing blocks fill idle BW while attention
// blocks retire -- attn uses <5% of HBM BW).
#define CVT1_BLOCKS 3072u   // 786432 f4 / 256

__global__ __launch_bounds__(256) void k_pre(const float* __restrict__ wq,
                                             const float* __restrict__ wk,
                                             const float* __restrict__ wv,
                                             unsigned short* __restrict__ wqkb,
                                             unsigned short* __restrict__ wvb,
                                             const float* __restrict__ x,
                                             const float* __restrict__ ln1,
                                             unsigned short* __restrict__ xn) {
  if (blockIdx.x < CVT1_BLOCKS) {
    const unsigned i = blockIdx.x * 256u + threadIdx.x;   // < 786432 exactly
    const float* src; unsigned short* dst; unsigned loc;
    if (i < 262144u)      { src = wq; dst = wqkb;            loc = i; }
    else if (i < 524288u) { src = wk; dst = wqkb + 1048576u; loc = i - 262144u; }
    else                  { src = wv; dst = wvb;             loc = i - 524288u; }
    float4 v = reinterpret_cast<const float4*>(src)[loc];
    ushort4 o;
    o.x = f2bf(v.x); o.y = f2bf(v.y); o.z = f2bf(v.z); o.w = f2bf(v.w);
    reinterpret_cast<ushort4*>(dst)[loc] = o;
  } else {
    const int row = (int)(blockIdx.x - CVT1_BLOCKS);
    const float4 v = reinterpret_cast<const float4*>(x + (size_t)row * DM)[threadIdx.x];
    float ss = v.x * v.x + v.y * v.y + v.z * v.z + v.w * v.w;
#pragma unroll
    for (int off = 32; off > 0; off >>= 1) ss += __shfl_down(ss, off);
    __shared__ float red[4];
    if ((threadIdx.x & 63) == 0) red[threadIdx.x >> 6] = ss;
    __syncthreads();
    const float tot  = red[0] + red[1] + red[2] + red[3];
    const float rden = rsqrtf(tot * (1.0f / DM) + 1e-5f);
    const float4 wv4 = reinterpret_cast<const float4*>(ln1)[threadIdx.x];
    ushort4 o;
    o.x = f2bf(v.x * wv4.x * rden);
    o.y = f2bf(v.y * wv4.y * rden);
    o.z = f2bf(v.z * wv4.z * rden);
    o.w = f2bf(v.w * wv4.w * rden);
    reinterpret_cast<ushort4*>(xn + (size_t)row * DM)[threadIdx.x] = o;
  }
}

// ---------------- RMSNorm: fp32 in -> bf16 out (ln2, standalone) ----------------
__global__ __launch_bounds__(256) void k_rmsnorm(const float* __restrict__ x,
                                                 const float* __restrict__ w,
                                                 unsigned short* __restrict__ out) {
  const int row = blockIdx.x;
  const float4 v = reinterpret_cast<const float4*>(x + (size_t)row * DM)[threadIdx.x];
  float ss = v.x * v.x + v.y * v.y + v.z * v.z + v.w * v.w;
#pragma unroll
  for (int off = 32; off > 0; off >>= 1) ss += __shfl_down(ss, off);
  __shared__ float red[4];
  if ((threadIdx.x & 63) == 0) red[threadIdx.x >> 6] = ss;
  __syncthreads();
  const float tot  = red[0] + red[1] + red[2] + red[3];
  const float rden = rsqrtf(tot * (1.0f / DM) + 1e-5f);
  const float4 wv = reinterpret_cast<const float4*>(w)[threadIdx.x];
  ushort4 o;
  o.x = f2bf(v.x * wv.x * rden);
  o.y = f2bf(v.y * wv.y * rden);
  o.z = f2bf(v.z * wv.z * rden);
  o.w = f2bf(v.w * wv.w * rden);
  reinterpret_cast<ushort4*>(out + (size_t)row * DM)[threadIdx.x] = o;
}

// ---------------- shared GEMM body: 128xTN tile, BK=32 (r13-proven path) ----------------
// Virtualized (vbid, vgx, vnb) so two GEMMs share one dispatch at their
// individually-best tile configs. Row-major LDS, coalesced staging (4 lanes
// per 64B row) + granule XOR, double-buffered 2-phase K-loop.
// PRESCALE: cols < DM scaled by 0.125*log2e (Q softmax-scale fold).
template <int TN, bool PRESCALE>
__device__ __forceinline__ void gemm_body_bk32(const unsigned short* __restrict__ A,
                                               const unsigned short* __restrict__ B,
                                               unsigned short* __restrict__ C,
                                               int M, int N, int K,
                                               unsigned vbid, unsigned vgx, unsigned vnb,
                                               unsigned short* AsP, unsigned short* BsP) {
  constexpr int NW = TN / 128;
  const int t  = threadIdx.x;
  const int w  = t >> 6;
  const int l  = t & 63;
  const int wr = w >> 1, wc = w & 1;
  const int lr = l & 15, lk = l >> 4;

  const unsigned cpx = vnb >> 3;
  const unsigned sw  = (vbid & 7) * cpx + (vbid >> 3);
  const int m0 = (int)(sw / vgx) * 128;
  const int n0 = (int)(sw % vgx) * TN;

  const int srow = t >> 2;                    // 0..63, 4 lanes per 64B row
  const int sgr  = (t & 3) ^ (srow & 3);      // pre-swizzled source granule

  auto stage = [&](int buf, int k0) {
#pragma unroll
    for (int r = 0; r < 2; ++r) {
      const unsigned short* ga = A + (size_t)(m0 + r * 64 + srow) * K + k0 + 8 * sgr;
      __builtin_amdgcn_global_load_lds((__attribute__((address_space(1))) void*)ga,
                                       (__attribute__((address_space(3))) void*)(AsP + buf * 4096 + r * 2048 + w * 512),
                                       16, 0, 0);
    }
#pragma unroll
    for (int r = 0; r < 2 * NW; ++r) {
      const unsigned short* gb = B + (size_t)(n0 + r * 64 + srow) * K + k0 + 8 * sgr;
      __builtin_amdgcn_global_load_lds((__attribute__((address_space(1))) void*)gb,
                                       (__attribute__((address_space(3))) void*)(BsP + buf * 4096 * NW + r * 2048 + w * 512),
                                       16, 0, 0);
    }
  };

  f32x4 acc[4][4 * NW] = {};

  stage(0, 0);
  const int nIt = K >> 5;
  for (int it = 0; it < nIt; ++it) {
    const int buf = it & 1;
    __syncthreads();                          // drains vmcnt -> buf ready; WAR-safe
    if (it + 1 < nIt) stage(buf ^ 1, (it + 1) << 5);

    bf16x8 af[4], bf[4 * NW];
#pragma unroll
    for (int m = 0; m < 4; ++m)
      af[m] = *reinterpret_cast<const bf16x8*>(
          AsP + buf * 4096 + (wr * 64 + m * 16 + lr) * 32 + 8 * (lk ^ (lr & 3)));
#pragma unroll
    for (int n = 0; n < 4 * NW; ++n)
      bf[n] = *reinterpret_cast<const bf16x8*>(
          BsP + buf * 4096 * NW + (wc * 64 * NW + n * 16 + lr) * 32 + 8 * (lk ^ (lr & 3)));
#pragma unroll
    for (int m = 0; m < 4; ++m)
#pragma unroll
      for (int n = 0; n < 4 * NW; ++n)
        acc[m][n] = __builtin_amdgcn_mfma_f32_16x16x32_bf16(af[m], bf[n], acc[m][n], 0, 0, 0);
  }

#pragma unroll
  for (int m = 0; m < 4; ++m) {
#pragma unroll
    for (int n = 0; n < 4 * NW; ++n) {
#pragma unroll
      for (int r = 0; r < 4; ++r) {
        const size_t row = (size_t)(m0 + wr * 64 + m * 16 + lk * 4 + r);
        const size_t col = (size_t)(n0 + wc * 64 * NW + n * 16 + lr);
        const float sc = (PRESCALE && col < DM) ? 0.18033688011f : 1.0f;  // 0.125*log2(e)
        C[row * N + col] = f2bf(acc[m][n][r] * sc);
      }
    }
  }
}

// ---------------- fused QK-projection + V^T GEMM (one dispatch, 1024 blocks) ----------------
// Blocks 0..511:  qk[8192x2048] = xn @ wqk^T, TN=256 (the r13 42us config), vgrid 8x64.
// Blocks 512..1023: vtb[1024x8192] = wv @ xn^T, TN=128 (the r13 27us config), vgrid 64x8.
// Shared 48KB LDS pool (VT uses the first half of Bs). Independent consumers
// of xn; fusion overlaps the tails and removes a launch gap.
__global__ __launch_bounds__(256, 2) void k_qkvt(const unsigned short* __restrict__ xn,
                                                 const unsigned short* __restrict__ wqkb,
                                                 unsigned short* __restrict__ qk,
                                                 const unsigned short* __restrict__ wvb,
                                                 unsigned short* __restrict__ vtb) {
  alignas(16) __shared__ unsigned short As[2][128 * 32];   // 16 KB
  alignas(16) __shared__ unsigned short Bs[2][256 * 32];   // 32 KB
  const unsigned bid = blockIdx.x;
  if (bid < 512u) {
    gemm_body_bk32<256, true >(xn, wqkb, qk, NROWS, 2 * DM, DM, bid, 8, 512, &As[0][0], &Bs[0][0]);
  } else {
    gemm_body_bk32<128, false>(wvb, xn, vtb, DM, NROWS, DM, bid - 512u, 64, 512, &As[0][0], &Bs[0][0]);
  }
}

// ---------------- NT GEMM: C(MxN) = A(MxK,bf16) * B(NxK,bf16)^T ----------------
// r9-proven structure, templated on TN (128/256) and BK (32/64).
// r10: never trade staging coalescing for LDS-conflict-freedom. r13: TN=256
// only when grid >= 2 blocks/CU. r16: BK=64 for TN=128 (barrier-stall bound).
// EPI: 1 fp32 = acc + res, 2 bf16 gelu.
template <int EPI, int TN, int BK>
__global__ __launch_bounds__(256, 2) void k_gemm_nt(const unsigned short* __restrict__ A,
                                                    const unsigned short* __restrict__ B,
                                                    void* __restrict__ Cv,
                                                    const float* __restrict__ res,
                                                    int M, int N, int K) {
  constexpr int NW = TN / 128;
  alignas(16) __shared__ unsigned short As[2][128 * BK];
  alignas(16) __shared__ unsigned short Bs[2][128 * NW * BK];
  const int t  = threadIdx.x;
  const int w  = t >> 6;
  const int l  = t & 63;
  const int wr = w >> 1, wc = w & 1;
  const int lr = l & 15, lk = l >> 4;

  const unsigned bid = blockIdx.y * gridDim.x + blockIdx.x;
  const unsigned cpx = (gridDim.x * gridDim.y) >> 3;
  const unsigned sw  = (bid & 7) * cpx + (bid >> 3);
  const int m0 = (int)(sw / gridDim.x) * 128;
  const int n0 = (int)(sw % gridDim.x) * TN;

  auto stage = [&](int buf, int k0) {
    if constexpr (BK == 32) {
      const int srow = t >> 2;
      const int sgr  = (t & 3) ^ (srow & 3);
#pragma unroll
      for (int r = 0; r < 2; ++r) {
        const unsigned short* ga = A + (size_t)(m0 + r * 64 + srow) * K + k0 + 8 * sgr;
        __builtin_amdgcn_global_load_lds((__attribute__((address_space(1))) void*)ga,
                                         (__attribute__((address_space(3))) void*)(&As[buf][r * 2048 + w * 512]),
                                         16, 0, 0);
      }
#pragma unroll
      for (int r = 0; r < 2 * NW; ++r) {
        const unsigned short* gb = B + (size_t)(n0 + r * 64 + srow) * K + k0 + 8 * sgr;
        __builtin_amdgcn_global_load_lds((__attribute__((address_space(1))) void*)gb,
                                         (__attribute__((address_space(3))) void*)(&Bs[buf][r * 2048 + w * 512]),
                                         16, 0, 0);
      }
    } else {
      const int srow8 = l >> 3;
      const int g     = l & 7;
#pragma unroll
      for (int i = 0; i < 4; ++i) {
        const int row = i * 32 + w * 8 + srow8;
        const int sg  = g ^ (row & 7);
        const unsigned short* ga = A + (size_t)(m0 + row) * K + k0 + 8 * sg;
        __builtin_amdgcn_global_load_lds((__attribute__((address_space(1))) void*)ga,
                                         (__attribute__((address_space(3))) void*)(&As[buf][i * 2048 + w * 512]),
                                         16, 0, 0);
        const unsigned short* gb = B + (size_t)(n0 + row) * K + k0 + 8 * sg;
        __builtin_amdgcn_global_load_lds((__attribute__((address_space(1))) void*)gb,
                                         (__attribute__((address_space(3))) void*)(&Bs[buf][i * 2048 + w * 512]),
                                         16, 0, 0);
      }
    }
  };

  f32x4 acc[4][4 * NW] = {};

  stage(0, 0);
  const int nIt = K / BK;
  for (int it = 0; it < nIt; ++it) {
    const int buf = it & 1;
    __syncthreads();
    if (it + 1 < nIt) stage(buf ^ 1, (it + 1) * BK);

    if constexpr (BK == 32) {
      bf16x8 af[4], bf[4 * NW];
#pragma unroll
      for (int m = 0; m < 4; ++m)
        af[m] = *reinterpret_cast<const bf16x8*>(
            &As[buf][(wr * 64 + m * 16 + lr) * 32 + 8 * (lk ^ (lr & 3))]);
#pragma unroll
      for (int n = 0; n < 4 * NW; ++n)
        bf[n] = *reinterpret_cast<const bf16x8*>(
            &Bs[buf][(wc * 64 * NW + n * 16 + lr) * 32 + 8 * (lk ^ (lr & 3))]);
#pragma unroll
      for (int m = 0; m < 4; ++m)
#pragma unroll
        for (int n = 0; n < 4 * NW; ++n)
          acc[m][n] = __builtin_amdgcn_mfma_f32_16x16x32_bf16(af[m], bf[n], acc[m][n], 0, 0, 0);
    } else {
#pragma unroll
      for (int kk = 0; kk < 2; ++kk) {
        bf16x8 af[4], bf[4];
#pragma unroll
        for (int m = 0; m < 4; ++m)
          af[m] = *reinterpret_cast<const bf16x8*>(
              &As[buf][(wr * 64 + m * 16 + lr) * 64 + 8 * ((4 * kk + lk) ^ (lr & 7))]);
#pragma unroll
        for (int n = 0; n < 4; ++n)
          bf[n] = *reinterpret_cast<const bf16x8*>(
              &Bs[buf][(wc * 64 + n * 16 + lr) * 64 + 8 * ((4 * kk + lk) ^ (lr & 7))]);
#pragma unroll
        for (int m = 0; m < 4; ++m)
#pragma unroll
          for (int n = 0; n < 4; ++n)
            acc[m][n] = __builtin_amdgcn_mfma_f32_16x16x32_bf16(af[m], bf[n], acc[m][n], 0, 0, 0);
      }
    }
  }

#pragma unroll
  for (int m = 0; m < 4; ++m) {
#pragma unroll
    for (int n = 0; n < 4 * NW; ++n) {
#pragma unroll
      for (int r = 0; r < 4; ++r) {
        const size_t row = (size_t)(m0 + wr * 64 + m * 16 + lk * 4 + r);
        const size_t col = (size_t)(n0 + wc * 64 * NW + n * 16 + lr);
        const float a = acc[m][n][r];
        if constexpr (EPI == 1) {
          ((float*)Cv)[row * N + col] = a + res[row * N + col];
        } else {
          // GELU, tanh/exp2 form
          const float h2 = a * a;
          const float e  = exp2f(a * (2.30221535f + 0.10295355f * h2));
          const float g  = a - a / (e + 1.0f);
          ((unsigned short*)Cv)[row * N + col] = f2bf(g);
        }
      }
    }
  }
}

// ---------------- Flash causal attention (r19) + trailing wo/w1/w2 f2bf blocks ----------------
// Blocks 0..1023: attention (64-row folded q-pairs, KVBLK=128, tree softmax,
// setprio, defer-max, XCD-grouped: bid&15 = h). Blocks 1024..10239: streaming
// f2bf of wo/w1/w2 -- attention uses <5% HBM BW, so these fill idle bandwidth
// as attn blocks retire; their outputs are consumed only by LATER dispatches.
#define ATTN_BLOCKS 1024u
#define CVT2_BLOCKS 9216u   // 2359296 f4 / 256

__global__ __launch_bounds__(256, 3) void k_attn(const unsigned short* __restrict__ QK,
                                                 const unsigned short* __restrict__ VT,
                                                 unsigned short* __restrict__ O,
                                                 const float* __restrict__ wo,
                                                 const float* __restrict__ w1,
                                                 const float* __restrict__ w2,
                                                 unsigned short* __restrict__ wob,
                                                 unsigned short* __restrict__ w1b,
                                                 unsigned short* __restrict__ w2b) {
  if (blockIdx.x >= ATTN_BLOCKS) {
    const unsigned i = (blockIdx.x - ATTN_BLOCKS) * 256u + threadIdx.x;   // < 2359296
    const float* src; unsigned short* dst; unsigned loc;
    if (i < 262144u)       { src = wo; dst = wob; loc = i; }
    else if (i < 1310720u) { src = w1; dst = w1b; loc = i - 262144u; }
    else                   { src = w2; dst = w2b; loc = i - 1310720u; }
    float4 v = reinterpret_cast<const float4*>(src)[loc];
    ushort4 o;
    o.x = f2bf(v.x); o.y = f2bf(v.y); o.z = f2bf(v.z); o.w = f2bf(v.w);
    reinterpret_cast<ushort4*>(dst)[loc] = o;
    return;
  }

  const int h   = blockIdx.x & 15;
  const int qtA = (blockIdx.x >> 4) & 15;     // 0..15
  const int qtB = 31 - qtA;                   // 31..16
  const int b   = blockIdx.x >> 8;
  const int t  = threadIdx.x, w = t >> 6, l = t & 63;
  const int lr = l & 15, lk = l >> 4;
  const size_t rowB = (size_t)b * SEQ;
  const int hoff  = h * DKH;
  const int qw2[2] = { qtA * 64 + 16 * w, qtB * 64 + 16 * w };

  alignas(16) __shared__ unsigned short Ks[128 * 64];      // 16 KB  [k][dk]
  alignas(16) __shared__ unsigned short Vt[64 * 128];      // 16 KB  [d][k]
  alignas(16) __shared__ unsigned short Ps[2][4][16 * 64]; // 16 KB

  char* const KsB = (char*)Ks;
  char* const VtB = (char*)Vt;

  auto stage = [&](int kb2) {
#pragma unroll
    for (int i = 0; i < 4; ++i) {
      const int krow = 32 * w + 8 * i + (l >> 3);
      const int sgk  = (l & 7) ^ (krow & 7);
      const unsigned short* gk = QK + (size_t)(rowB + kb2 + krow) * KSTR + DM + hoff + 8 * sgk;
      __builtin_amdgcn_global_load_lds((__attribute__((address_space(1))) void*)gk,
                                       (__attribute__((address_space(3))) void*)(KsB + w * 4096 + i * 1024),
                                       16, 0, 0);
      const int vrow = 16 * w + 4 * i + (l >> 4);
      const int sgv  = (l & 15) ^ (vrow & 15);
      const unsigned short* gv = VT + (size_t)(hoff + vrow) * NROWS + rowB + kb2 + 8 * sgv;
      __builtin_amdgcn_global_load_lds((__attribute__((address_space(1))) void*)gv,
                                       (__attribute__((address_space(3))) void*)(VtB + w * 4096 + i * 1024),
                                       16, 0, 0);
    }
  };

  bf16x8 qf[2][2];
#pragma unroll
  for (int s = 0; s < 2; ++s)
#pragma unroll
    for (int kk = 0; kk < 2; ++kk)
      qf[s][kk] = *reinterpret_cast<const bf16x8*>(
          QK + (rowB + qw2[s] + lr) * KSTR + hoff + 32 * kk + 8 * lk);

  f32x4 oacc[2][4] = {};
  float mrun[2] = {-1e30f, -1e30f};
  float lrun[2] = {0.0f, 0.0f};

  const int ktmax = qtB >> 1;                 // 128-key tiles
  for (int kt = 0; kt <= ktmax; ++kt) {
    const int kbase = kt * 128;
    __syncthreads();
    stage(kbase);
    __syncthreads();

#pragma unroll
    for (int h2 = 0; h2 < 2; ++h2) {
      const int kb = kbase + 64 * h2;
      const bool act[2] = { kb <= qw2[0] + 15, kb <= qw2[1] + 15 };
      if (!act[0] && !act[1]) continue;
      const char* Kc = KsB + h2 * 8192;

      f32x4 sacc[2][4] = {};
      __builtin_amdgcn_s_setprio(1);
#pragma unroll
      for (int tt = 0; tt < 4; ++tt) {
        bf16x8 kf0 = *reinterpret_cast<const bf16x8*>(Kc + (16 * tt + lr) * 128 + 16 * ((lk + 0) ^ (lr & 7)));
        bf16x8 kf1 = *reinterpret_cast<const bf16x8*>(Kc + (16 * tt + lr) * 128 + 16 * ((lk + 4) ^ (lr & 7)));
#pragma unroll
        for (int s = 0; s < 2; ++s) {
          if (!act[s]) continue;
          sacc[s][tt] = __builtin_amdgcn_mfma_f32_16x16x32_bf16(kf0, qf[s][0], sacc[s][tt], 0, 0, 0);
          sacc[s][tt] = __builtin_amdgcn_mfma_f32_16x16x32_bf16(kf1, qf[s][1], sacc[s][tt], 0, 0, 0);
        }
      }
      __builtin_amdgcn_s_setprio(0);

#pragma unroll
      for (int s = 0; s < 2; ++s) {
        if (!act[s]) continue;
        const int qw = qw2[s];
        char* const PsSB = (char*)(Ps[s][w]);
        const int qg = qw + lr;
        float sv[4][4];
        if (kb + 63 > qw) {
#pragma unroll
          for (int tt = 0; tt < 4; ++tt)
#pragma unroll
            for (int r = 0; r < 4; ++r) {
              const int kg = kb + 16 * tt + 4 * lk + r;
              sv[tt][r] = (kg > qg) ? -1e30f : sacc[s][tt][r];
            }
        } else {
#pragma unroll
          for (int tt = 0; tt < 4; ++tt)
#pragma unroll
            for (int r = 0; r < 4; ++r) sv[tt][r] = sacc[s][tt][r];
        }
        const float a0 = fmaxf(fmaxf(sv[0][0], sv[0][1]), sv[0][2]);
        const float a1 = fmaxf(fmaxf(sv[0][3], sv[1][0]), sv[1][1]);
        const float a2 = fmaxf(fmaxf(sv[1][2], sv[1][3]), sv[2][0]);
        const float a3 = fmaxf(fmaxf(sv[2][1], sv[2][2]), sv[2][3]);
        const float a4 = fmaxf(fmaxf(sv[3][0], sv[3][1]), sv[3][2]);
        float tm = fmaxf(fmaxf(fmaxf(a0, a1), a2), fmaxf(fmaxf(a3, a4), sv[3][3]));
        tm = fmaxf(tm, __shfl_xor(tm, 16));
        tm = fmaxf(tm, __shfl_xor(tm, 32));
        float mref = mrun[s];
        if (__any(tm > mref + 8.0f)) {            // defer-max
          const float mnew  = fmaxf(mref, tm);
          const float alpha = exp2f(mref - mnew);
#pragma unroll
          for (int r = 0; r < 4; ++r) {
            const float ar = __shfl(alpha, 4 * lk + r);
#pragma unroll
            for (int dn = 0; dn < 4; ++dn) oacc[s][dn][r] *= ar;
          }
          lrun[s] *= alpha;
          mrun[s] = mnew;
          mref = mnew;
        }
        float p[4][4];
        unsigned short pb[4][4];
#pragma unroll
        for (int tt = 0; tt < 4; ++tt)
#pragma unroll
          for (int r = 0; r < 4; ++r) {
            p[tt][r] = exp2f(sv[tt][r] - mref);
            pb[tt][r] = __builtin_bit_cast(unsigned short, static_cast<__bf16>(p[tt][r]));
          }
        float t0 = (p[0][0] + p[0][1]) + (p[0][2] + p[0][3]);
        float t1 = (p[1][0] + p[1][1]) + (p[1][2] + p[1][3]);
        float t2 = (p[2][0] + p[2][1]) + (p[2][2] + p[2][3]);
        float t3 = (p[3][0] + p[3][1]) + (p[3][2] + p[3][3]);
        float ts = (t0 + t1) + (t2 + t3);
        ts += __shfl_xor(ts, 16);
        ts += __shfl_xor(ts, 32);
        lrun[s] += ts;
#pragma unroll
        for (int tt = 0; tt < 4; ++tt) {
          u16x4 pw = {pb[tt][0], pb[tt][1], pb[tt][2], pb[tt][3]};
          *reinterpret_cast<u16x4*>(
              PsSB + lr * 128 + ((32 * tt + 8 * lk) ^ (16 * (lr & 7)))) = pw;
        }
      }

      asm volatile("" ::: "memory");

#pragma unroll
      for (int kk = 0; kk < 2; ++kk) {
        bf16x8 vf[4];
#pragma unroll
        for (int dn = 0; dn < 4; ++dn)
          vf[dn] = *reinterpret_cast<const bf16x8*>(
              VtB + (16 * dn + lr) * 256 + 16 * ((8 * h2 + 4 * kk + lk) ^ lr));
        __builtin_amdgcn_s_setprio(1);
#pragma unroll
        for (int s = 0; s < 2; ++s) {
          if (!act[s]) continue;
          char* const PsSB = (char*)(Ps[s][w]);
          bf16x8 pa = *reinterpret_cast<const bf16x8*>(
              PsSB + lr * 128 + ((64 * kk + 16 * lk) ^ (16 * (lr & 7))));
#pragma unroll
          for (int dn = 0; dn < 4; ++dn)
            oacc[s][dn] = __builtin_amdgcn_mfma_f32_16x16x32_bf16(pa, vf[dn], oacc[s][dn], 0, 0, 0);
        }
        __builtin_amdgcn_s_setprio(0);
      }

      asm volatile("" ::: "memory");
    }
  }

#pragma unroll
  for (int s = 0; s < 2; ++s)
#pragma unroll
    for (int r = 0; r < 4; ++r) {
      const float li = 1.0f / __shfl(lrun[s], 4 * lk + r);
      const size_t row = rowB + qw2[s] + 4 * lk + r;
#pragma unroll
      for (int dn = 0; dn < 4; ++dn)
        O[row * DM + hoff + 16 * dn + lr] = f2bf(oacc[s][dn][r] * li);
    }
}

// ---------------- launch ----------------
extern "C" void kernel_launch(void* const* d_in, const int* in_sizes, int n_in,
                              void* d_out, int out_size, void* d_ws, size_t ws_size,
                              hipStream_t stream) {
  const float* x   = (const float*)d_in[0];
  const float* ln1 = (const float*)d_in[1];
  const float* ln2 = (const float*)d_in[2];
  const float* wq  = (const float*)d_in[3];
  const float* wk  = (const float*)d_in[4];
  const float* wv  = (const float*)d_in[5];
  const float* wo  = (const float*)d_in[6];
  const float* w1  = (const float*)d_in[7];
  const float* w2  = (const float*)d_in[8];

  char* ws = (char*)d_ws;
  size_t off = 0;
  auto take = [&](size_t bytes) { void* p = ws + off; off += bytes; return p; };
  unsigned short* wqkb = (unsigned short*)take((size_t)2 * DM * DM * 2);   // 4 MB (Q,K fused)
  unsigned short* wvb  = (unsigned short*)take((size_t)DM * DM * 2);       // 2 MB
  unsigned short* wob  = (unsigned short*)take((size_t)DM * DM * 2);       // 2 MB
  unsigned short* w1b  = (unsigned short*)take((size_t)DFF * DM * 2);      // 8 MB
  unsigned short* w2b  = (unsigned short*)take((size_t)DM * DFF * 2);      // 8 MB
  unsigned short* qk   = (unsigned short*)take((size_t)NROWS * 2 * DM * 2); // 32 MB
  unsigned short* xn   = (unsigned short*)take((size_t)NROWS * DM * 2);    // 16 MB (ln1 out, reused attn-out)
  unsigned short* vtb  = (unsigned short*)take((size_t)DM * NROWS * 2);    // 16 MB V^T [DM][NROWS]
  float*          yb   = (float*)take((size_t)NROWS * DM * 4);             // 32 MB fp32 residual
  unsigned short* hb   = (unsigned short*)take((size_t)NROWS * DFF * 2);   // 64 MB
  unsigned short* yn   = qk;   // ln2 out aliases qk (dead after attn)

  // prologue: f2bf(wq,wk,wv) + rmsnorm1
  k_pre<<<dim3(CVT1_BLOCKS + NROWS), dim3(256), 0, stream>>>(wq, wk, wv, wqkb, wvb, x, ln1, xn);

  // fused QK projection (TN=256, Q pre-scaled) + V^T GEMM (TN=128)
  k_qkvt<<<dim3(1024), dim3(256), 0, stream>>>(xn, wqkb, qk, wvb, vtb);

  // attention + trailing f2bf(wo,w1,w2)
  k_attn<<<dim3(ATTN_BLOCKS + CVT2_BLOCKS), dim3(256), 0, stream>>>(
      qk, vtb, xn, wo, w1, w2, wob, w1b, w2b);

  // WO projection + residual: 128x128, BK=64
  k_gemm_nt<1, 128, 64><<<dim3(DM / 128, NROWS / 128), dim3(256), 0, stream>>>(
      xn, wob, yb, x, NROWS, DM, DM);

  k_rmsnorm<<<dim3(NROWS), dim3(256), 0, stream>>>(yb, ln2, yn);

  // FFN1: 128x256 tile, BK=32 (grid 16x64 = 1024 blocks)
  k_gemm_nt<2, 256, 32><<<dim3(DFF / 256, NROWS / 128), dim3(256), 0, stream>>>(
      yn, w1b, hb, nullptr, NROWS, DFF, DM);
  // FFN2 + residual -> d_out: 128x128, BK=64
  k_gemm_nt<1, 128, 64><<<dim3(DM / 128, NROWS / 128), dim3(256), 0, stream>>>(
      hb, w2b, (float*)d_out, yb, NROWS, DM, DFF);
}